// Round 1
// baseline (4606.178 us; speedup 1.0000x reference)
//
#include <hip/hip_runtime.h>
#include <math.h>

#define IN_DIM 128
#define H1 64
#define H2 32
#define NC 8

// ---------------- degree / norm prep ----------------

__global__ void k_init_deg(unsigned int* deg, int n) {
  int i = blockIdx.x * 256 + threadIdx.x;
  if (i < n) deg[i] = 1u;  // self-loop
}

__global__ void k_count_deg(const int* __restrict__ dst, unsigned int* deg, int E) {
  int i = blockIdx.x * 256 + threadIdx.x;
  if (i < E) atomicAdd(&deg[dst[i]], 1u);
}

__global__ void k_dinv(const unsigned int* __restrict__ deg, float* dinv, int n) {
  int i = blockIdx.x * 256 + threadIdx.x;
  if (i < n) dinv[i] = rsqrtf((float)deg[i]);
}

__global__ void k_norm(const int* __restrict__ src, const int* __restrict__ dst,
                       const float* __restrict__ dinv, float* norm, int E) {
  int i = blockIdx.x * 256 + threadIdx.x;
  if (i < E) norm[i] = dinv[src[i]] * dinv[dst[i]];
}

// ---------------- projection 1: h1p = x @ W1^T  [n,128]->[n,64] ----------------
// 16 rows per block, 256 threads: o = tid&63, each thread does 4 rows.

__global__ void k_proj1(const float4* __restrict__ x4, const float* __restrict__ W1,
                        float* __restrict__ h1p, int n) {
  __shared__ float xs[16][IN_DIM];      // 8 KB
  __shared__ float wt[IN_DIM][H1 + 1];  // transposed, padded: wt[k][o]
  int tid = threadIdx.x;
  int row0 = blockIdx.x * 16;

  // stage W1 (64x128 floats) transposed into LDS
  for (int i = tid; i < (H1 * IN_DIM / 4); i += 256) {
    float4 w = ((const float4*)W1)[i];
    int o = (i * 4) / IN_DIM;
    int k = (i * 4) % IN_DIM;
    wt[k + 0][o] = w.x; wt[k + 1][o] = w.y; wt[k + 2][o] = w.z; wt[k + 3][o] = w.w;
  }
  // stage 16 rows of x
  for (int i = tid; i < 16 * IN_DIM / 4; i += 256) {
    int r = (i * 4) / IN_DIM, k = (i * 4) % IN_DIM;
    int row = row0 + r;
    if (row < n)
      *((float4*)&xs[r][k]) = x4[(size_t)row * (IN_DIM / 4) + k / 4];
  }
  __syncthreads();

  int o = tid & 63, rq = tid >> 6;
  float a0 = 0.f, a1 = 0.f, a2 = 0.f, a3 = 0.f;
  for (int k = 0; k < IN_DIM; ++k) {
    float w = wt[k][o];
    a0 += xs[rq * 4 + 0][k] * w;
    a1 += xs[rq * 4 + 1][k] * w;
    a2 += xs[rq * 4 + 2][k] * w;
    a3 += xs[rq * 4 + 3][k] * w;
  }
  int r = row0 + rq * 4;
  if (r + 0 < n) h1p[(size_t)(r + 0) * H1 + o] = a0;
  if (r + 1 < n) h1p[(size_t)(r + 1) * H1 + o] = a1;
  if (r + 2 < n) h1p[(size_t)(r + 2) * H1 + o] = a2;
  if (r + 3 < n) h1p[(size_t)(r + 3) * H1 + o] = a3;
}

// ---------------- self-loop init: outp = dinv^2 * hp ----------------
// s = log2(floats_per_row/4): 4 for 64 feats, 3 for 32 feats

__global__ void k_selfinit(const float4* __restrict__ hp, const float* __restrict__ dinv,
                           float4* __restrict__ outp, int n, int s) {
  int i = blockIdx.x * 256 + threadIdx.x;
  if (i >= (n << s)) return;
  int node = i >> s;
  float d = dinv[node];
  float sc = d * d;
  float4 v = hp[i];
  v.x *= sc; v.y *= sc; v.z *= sc; v.w *= sc;
  outp[i] = v;
}

// ---------------- edge aggregation: out[dst] += norm * hp[src] ----------------
// thread = (edge, float4-group); s = log2(groups per row)

__global__ void k_edge_agg(const int* __restrict__ src, const int* __restrict__ dst,
                           const float* __restrict__ norm, const float4* __restrict__ hp,
                           float* __restrict__ outp, int E, int s) {
  long long idx = (long long)blockIdx.x * 256 + threadIdx.x;
  if (idx >= ((long long)E << s)) return;
  int e = (int)(idx >> s);
  int q = (int)(idx & ((1 << s) - 1));
  float nm = norm[e];
  int sv = src[e], dv = dst[e];
  float4 v = hp[((size_t)sv << s) + q];
  float* ob = outp + ((((size_t)dv << s) + q) << 2);
  unsafeAtomicAdd(ob + 0, v.x * nm);
  unsafeAtomicAdd(ob + 1, v.y * nm);
  unsafeAtomicAdd(ob + 2, v.z * nm);
  unsafeAtomicAdd(ob + 3, v.w * nm);
}

// ---------------- projection 2: h2p = relu(out1 + b1) @ W2^T  [n,64]->[n,32] ----------------
// 32 rows per block, 256 threads: o = tid&31, each thread does 4 rows.

__global__ void k_proj2(const float* __restrict__ out1, const float* __restrict__ b1,
                        const float* __restrict__ W2, float* __restrict__ h2p, int n) {
  __shared__ float xs[32][H1];        // 8 KB (relu'd rows)
  __shared__ float wt[H1][H2 + 1];    // transposed, padded
  int tid = threadIdx.x;
  int row0 = blockIdx.x * 32;

  for (int i = tid; i < (H2 * H1 / 4); i += 256) {  // 512 f4
    float4 w = ((const float4*)W2)[i];
    int o = (i * 4) / H1;
    int k = (i * 4) % H1;
    wt[k + 0][o] = w.x; wt[k + 1][o] = w.y; wt[k + 2][o] = w.z; wt[k + 3][o] = w.w;
  }
  for (int i = tid; i < 32 * H1 / 4; i += 256) {  // 512 f4
    int r = (i * 4) / H1, k = (i * 4) % H1;
    int row = row0 + r;
    if (row < n) {
      float4 v = ((const float4*)out1)[(size_t)row * (H1 / 4) + k / 4];
      float4 bb = ((const float4*)b1)[k / 4];
      v.x = fmaxf(v.x + bb.x, 0.f);
      v.y = fmaxf(v.y + bb.y, 0.f);
      v.z = fmaxf(v.z + bb.z, 0.f);
      v.w = fmaxf(v.w + bb.w, 0.f);
      *((float4*)&xs[r][k]) = v;
    }
  }
  __syncthreads();

  int o = tid & 31, rg = tid >> 5;  // rg in 0..7
  float a0 = 0.f, a1 = 0.f, a2 = 0.f, a3 = 0.f;
  for (int k = 0; k < H1; ++k) {
    float w = wt[k][o];
    a0 += xs[rg * 4 + 0][k] * w;
    a1 += xs[rg * 4 + 1][k] * w;
    a2 += xs[rg * 4 + 2][k] * w;
    a3 += xs[rg * 4 + 3][k] * w;
  }
  int r = row0 + rg * 4;
  if (r + 0 < n) h2p[(size_t)(r + 0) * H2 + o] = a0;
  if (r + 1 < n) h2p[(size_t)(r + 1) * H2 + o] = a1;
  if (r + 2 < n) h2p[(size_t)(r + 2) * H2 + o] = a2;
  if (r + 3 < n) h2p[(size_t)(r + 3) * H2 + o] = a3;
}

// ---------------- soft tree head ----------------
// 8 nodes per block of 256 threads.

__global__ void k_tree(const float* __restrict__ out2, const float* __restrict__ b2,
                       const float* __restrict__ gate_w, const float* __restrict__ gate_b,
                       const float* __restrict__ leaf_w, float* __restrict__ out, int n) {
  __shared__ float h2s[8 * H2];
  __shared__ float gws[H2][H2 + 1];
  __shared__ float gbias[H2];
  __shared__ float lws[H2 * NC];
  __shared__ float gs[8 * H2];
  int tid = threadIdx.x;
  int node0 = blockIdx.x * 8;

  {
    int node = node0 + (tid >> 5);
    if (node < n) h2s[tid] = out2[(size_t)node * H2 + (tid & 31)] + b2[tid & 31];
    else h2s[tid] = 0.f;
  }
  for (int i = tid; i < H2 * H2; i += 256) gws[i >> 5][i & 31] = gate_w[i];
  if (tid < H2 * NC) lws[tid] = leaf_w[tid];
  if (tid < H2) gbias[tid] = gate_b[tid];
  __syncthreads();

  {
    int ln = tid >> 5, j = tid & 31;
    float g = gbias[j];
    for (int k = 0; k < H2; ++k) g += h2s[ln * H2 + k] * gws[j][k];
    gs[ln * H2 + j] = 1.0f / (1.0f + expf(-g));
  }
  __syncthreads();

  if (tid < 64) {
    int ln = tid >> 3, c = tid & 7;
    int node = node0 + ln;
    if (node < n) {
      float a = 0.f;
      for (int j = 0; j < H2; ++j) a += gs[ln * H2 + j] * lws[j * NC + c];
      out[(size_t)node * NC + c] = a;
    }
  }
}

// ---------------- host ----------------

extern "C" void kernel_launch(void* const* d_in, const int* in_sizes, int n_in,
                              void* d_out, int out_size, void* d_ws, size_t ws_size,
                              hipStream_t stream) {
  const float* x  = (const float*)d_in[0];
  const int*   ei = (const int*)d_in[1];
  const float* W1 = (const float*)d_in[2];
  const float* b1 = (const float*)d_in[3];
  const float* W2 = (const float*)d_in[4];
  const float* b2 = (const float*)d_in[5];
  const float* gw = (const float*)d_in[6];
  const float* gb = (const float*)d_in[7];
  const float* lw = (const float*)d_in[8];
  float* out = (float*)d_out;

  int n = in_sizes[0] / IN_DIM;
  int E = in_sizes[1] / 2;
  const int* src  = ei;
  const int* dstp = ei + E;

  // workspace layout (floats): deg[n] | dinv[n] | norm[E] | bufA[n*64] | bufB[n*64]
  unsigned int* deg = (unsigned int*)d_ws;
  float* dinv = (float*)d_ws + n;
  float* norm = dinv + n;
  float* bufA = norm + E;                 // h1p, then h2p (first n*32)
  float* bufB = bufA + (size_t)n * H1;    // out1, then out2 (first n*32)

  int gn = (n + 255) / 256;
  int gE = (E + 255) / 256;

  k_init_deg<<<gn, 256, 0, stream>>>(deg, n);
  k_count_deg<<<gE, 256, 0, stream>>>(dstp, deg, E);
  k_dinv<<<gn, 256, 0, stream>>>(deg, dinv, n);
  k_norm<<<gE, 256, 0, stream>>>(src, dstp, dinv, norm, E);

  // layer 1
  k_proj1<<<(n + 15) / 16, 256, 0, stream>>>((const float4*)x, W1, bufA, n);
  k_selfinit<<<(n * (H1 / 4) + 255) / 256, 256, 0, stream>>>(
      (const float4*)bufA, dinv, (float4*)bufB, n, 4);
  k_edge_agg<<<(int)(((long long)E * (H1 / 4) + 255) / 256), 256, 0, stream>>>(
      src, dstp, norm, (const float4*)bufA, bufB, E, 4);

  // layer 2 (h2p reuses bufA, out2 reuses... separate region: bufA holds h2p)
  k_proj2<<<(n + 31) / 32, 256, 0, stream>>>(bufB, b1, W2, bufA, n);
  k_selfinit<<<(n * (H2 / 4) + 255) / 256, 256, 0, stream>>>(
      (const float4*)bufA, dinv, (float4*)bufB, n, 3);
  k_edge_agg<<<(int)(((long long)E * (H2 / 4) + 255) / 256), 256, 0, stream>>>(
      src, dstp, norm, (const float4*)bufA, bufB, E, 3);

  // tree head
  k_tree<<<(n + 7) / 8, 256, 0, stream>>>(bufB, b2, gw, gb, lw, out, n);
}

// Round 2
// 1344.292 us; speedup vs baseline: 3.4265x; 3.4265x over previous
//
#include <hip/hip_runtime.h>
#include <math.h>

#define IN_DIM 128
#define H1 64
#define H2 32
#define NC 8

// ---------------- degree prep ----------------

__global__ void k_init_deg(unsigned int* deg, int n) {
  int i = blockIdx.x * 256 + threadIdx.x;
  if (i < n) deg[i] = 1u;  // self-loop
}

__global__ void k_count_deg(const int* __restrict__ dst, unsigned int* deg, int E) {
  int i = blockIdx.x * 256 + threadIdx.x;
  if (i < E) atomicAdd(&deg[dst[i]], 1u);
}

__global__ void k_dinv(const unsigned int* __restrict__ deg, float* dinv, int n) {
  int i = blockIdx.x * 256 + threadIdx.x;
  if (i < n) dinv[i] = rsqrtf((float)deg[i]);
}

// ---------------- exclusive scan of (deg-1) over n nodes, single block ----------------

__global__ __launch_bounds__(1024) void k_scan(const unsigned int* __restrict__ deg,
                                               int* __restrict__ off, int n) {
  __shared__ int part[1024];
  int tid = threadIdx.x;
  int chunk = (n + 1023) / 1024;
  int st = tid * chunk;
  int en = st + chunk; if (en > n) en = n;
  int s = 0;
  for (int i = st; i < en; ++i) s += (int)deg[i] - 1;
  part[tid] = s;
  __syncthreads();
  // Hillis-Steele inclusive scan
  for (int d = 1; d < 1024; d <<= 1) {
    int v = (tid >= d) ? part[tid - d] : 0;
    __syncthreads();
    part[tid] += v;
    __syncthreads();
  }
  int base = (tid == 0) ? 0 : part[tid - 1];
  for (int i = st; i < en; ++i) { off[i] = base; base += (int)deg[i] - 1; }
  if (tid == 1023) off[n] = part[1023];
}

__global__ void k_zero_u32(unsigned int* p, int n) {
  int i = blockIdx.x * 256 + threadIdx.x;
  if (i < n) p[i] = 0u;
}

// ---------------- CSR fill: csr_src/csr_norm grouped by dst ----------------

__global__ void k_fill(const int* __restrict__ src, const int* __restrict__ dst,
                       const float* __restrict__ dinv, const int* __restrict__ off,
                       unsigned int* __restrict__ cur, int* __restrict__ csr_src,
                       float* __restrict__ csr_norm, int E) {
  int e = blockIdx.x * 256 + threadIdx.x;
  if (e >= E) return;
  int d = dst[e], s = src[e];
  int pos = off[d] + (int)atomicAdd(&cur[d], 1u);
  csr_src[pos] = s;
  csr_norm[pos] = dinv[s] * dinv[d];
}

// ---------------- projection 1: h1p = x @ W1^T  [n,128]->[n,64] ----------------

__global__ void k_proj1(const float4* __restrict__ x4, const float* __restrict__ W1,
                        float* __restrict__ h1p, int n) {
  __shared__ float xs[16][IN_DIM];
  __shared__ float wt[IN_DIM][H1 + 1];
  int tid = threadIdx.x;
  int row0 = blockIdx.x * 16;

  for (int i = tid; i < (H1 * IN_DIM / 4); i += 256) {
    float4 w = ((const float4*)W1)[i];
    int o = (i * 4) / IN_DIM;
    int k = (i * 4) % IN_DIM;
    wt[k + 0][o] = w.x; wt[k + 1][o] = w.y; wt[k + 2][o] = w.z; wt[k + 3][o] = w.w;
  }
  for (int i = tid; i < 16 * IN_DIM / 4; i += 256) {
    int r = (i * 4) / IN_DIM, k = (i * 4) % IN_DIM;
    int row = row0 + r;
    if (row < n)
      *((float4*)&xs[r][k]) = x4[(size_t)row * (IN_DIM / 4) + k / 4];
  }
  __syncthreads();

  int o = tid & 63, rq = tid >> 6;
  float a0 = 0.f, a1 = 0.f, a2 = 0.f, a3 = 0.f;
  for (int k = 0; k < IN_DIM; ++k) {
    float w = wt[k][o];
    a0 += xs[rq * 4 + 0][k] * w;
    a1 += xs[rq * 4 + 1][k] * w;
    a2 += xs[rq * 4 + 2][k] * w;
    a3 += xs[rq * 4 + 3][k] * w;
  }
  int r = row0 + rq * 4;
  if (r + 0 < n) h1p[(size_t)(r + 0) * H1 + o] = a0;
  if (r + 1 < n) h1p[(size_t)(r + 1) * H1 + o] = a1;
  if (r + 2 < n) h1p[(size_t)(r + 2) * H1 + o] = a2;
  if (r + 3 < n) h1p[(size_t)(r + 3) * H1 + o] = a3;
}

// ---------------- CSR gather aggregation, 64 features ----------------
// One 64-lane wave per dst node; lane = feature. Fuses self-loop + bias + relu.

__global__ void k_agg64(const float* __restrict__ hp, const float* __restrict__ dinv,
                        const int* __restrict__ off, const int* __restrict__ csr_src,
                        const float* __restrict__ csr_norm, const float* __restrict__ b1,
                        float* __restrict__ outp, int n) {
  int wid = (blockIdx.x * 256 + threadIdx.x) >> 6;
  int lane = threadIdx.x & 63;
  if (wid >= n) return;
  float d = dinv[wid];
  float acc = d * d * hp[(size_t)wid * H1 + lane];
  int r0 = off[wid], r1 = off[wid + 1];
  int i = r0;
  // unroll by 2 for load pipelining
  for (; i + 1 < r1; i += 2) {
    int s0 = csr_src[i], s1 = csr_src[i + 1];
    float n0 = csr_norm[i], n1 = csr_norm[i + 1];
    float v0 = hp[(size_t)s0 * H1 + lane];
    float v1 = hp[(size_t)s1 * H1 + lane];
    acc += n0 * v0;
    acc += n1 * v1;
  }
  if (i < r1) {
    acc += csr_norm[i] * hp[(size_t)csr_src[i] * H1 + lane];
  }
  outp[(size_t)wid * H1 + lane] = fmaxf(acc + b1[lane], 0.f);
}

// ---------------- CSR gather aggregation, 32 features ----------------
// One wave per node; lanes 0-31 take even edges, 32-63 odd; shfl-combine.

__global__ void k_agg32(const float* __restrict__ hp, const float* __restrict__ dinv,
                        const int* __restrict__ off, const int* __restrict__ csr_src,
                        const float* __restrict__ csr_norm,
                        float* __restrict__ outp, int n) {
  int wid = (blockIdx.x * 256 + threadIdx.x) >> 6;
  int lane = threadIdx.x & 63;
  if (wid >= n) return;
  int half = lane >> 5, f = lane & 31;
  float d = dinv[wid];
  float acc = (half == 0) ? d * d * hp[(size_t)wid * H2 + f] : 0.f;
  int r0 = off[wid], r1 = off[wid + 1];
  for (int i = r0 + half; i < r1; i += 2) {
    int s = csr_src[i];
    float nm = csr_norm[i];
    acc += nm * hp[(size_t)s * H2 + f];
  }
  acc += __shfl_down(acc, 32, 64);
  if (half == 0) outp[(size_t)wid * H2 + f] = acc;
}

// ---------------- projection 2: h2p = out1 @ W2^T  [n,64]->[n,32] ----------------
// (out1 already has bias+relu applied by k_agg64 epilogue)

__global__ void k_proj2(const float* __restrict__ out1,
                        const float* __restrict__ W2, float* __restrict__ h2p, int n) {
  __shared__ float xs[32][H1];
  __shared__ float wt[H1][H2 + 1];
  int tid = threadIdx.x;
  int row0 = blockIdx.x * 32;

  for (int i = tid; i < (H2 * H1 / 4); i += 256) {
    float4 w = ((const float4*)W2)[i];
    int o = (i * 4) / H1;
    int k = (i * 4) % H1;
    wt[k + 0][o] = w.x; wt[k + 1][o] = w.y; wt[k + 2][o] = w.z; wt[k + 3][o] = w.w;
  }
  for (int i = tid; i < 32 * H1 / 4; i += 256) {
    int r = (i * 4) / H1, k = (i * 4) % H1;
    int row = row0 + r;
    if (row < n)
      *((float4*)&xs[r][k]) = ((const float4*)out1)[(size_t)row * (H1 / 4) + k / 4];
  }
  __syncthreads();

  int o = tid & 31, rg = tid >> 5;
  float a0 = 0.f, a1 = 0.f, a2 = 0.f, a3 = 0.f;
  for (int k = 0; k < H1; ++k) {
    float w = wt[k][o];
    a0 += xs[rg * 4 + 0][k] * w;
    a1 += xs[rg * 4 + 1][k] * w;
    a2 += xs[rg * 4 + 2][k] * w;
    a3 += xs[rg * 4 + 3][k] * w;
  }
  int r = row0 + rg * 4;
  if (r + 0 < n) h2p[(size_t)(r + 0) * H2 + o] = a0;
  if (r + 1 < n) h2p[(size_t)(r + 1) * H2 + o] = a1;
  if (r + 2 < n) h2p[(size_t)(r + 2) * H2 + o] = a2;
  if (r + 3 < n) h2p[(size_t)(r + 3) * H2 + o] = a3;
}

// ---------------- soft tree head ----------------

__global__ void k_tree(const float* __restrict__ out2, const float* __restrict__ b2,
                       const float* __restrict__ gate_w, const float* __restrict__ gate_b,
                       const float* __restrict__ leaf_w, float* __restrict__ out, int n) {
  __shared__ float h2s[8 * H2];
  __shared__ float gws[H2][H2 + 1];
  __shared__ float gbias[H2];
  __shared__ float lws[H2 * NC];
  __shared__ float gs[8 * H2];
  int tid = threadIdx.x;
  int node0 = blockIdx.x * 8;

  {
    int node = node0 + (tid >> 5);
    if (node < n) h2s[tid] = out2[(size_t)node * H2 + (tid & 31)] + b2[tid & 31];
    else h2s[tid] = 0.f;
  }
  for (int i = tid; i < H2 * H2; i += 256) gws[i >> 5][i & 31] = gate_w[i];
  if (tid < H2 * NC) lws[tid] = leaf_w[tid];
  if (tid < H2) gbias[tid] = gate_b[tid];
  __syncthreads();

  {
    int ln = tid >> 5, j = tid & 31;
    float g = gbias[j];
    for (int k = 0; k < H2; ++k) g += h2s[ln * H2 + k] * gws[j][k];
    gs[ln * H2 + j] = 1.0f / (1.0f + expf(-g));
  }
  __syncthreads();

  if (tid < 64) {
    int ln = tid >> 3, c = tid & 7;
    int node = node0 + ln;
    if (node < n) {
      float a = 0.f;
      for (int j = 0; j < H2; ++j) a += gs[ln * H2 + j] * lws[j * NC + c];
      out[(size_t)node * NC + c] = a;
    }
  }
}

// ---------------- host ----------------

extern "C" void kernel_launch(void* const* d_in, const int* in_sizes, int n_in,
                              void* d_out, int out_size, void* d_ws, size_t ws_size,
                              hipStream_t stream) {
  const float* x  = (const float*)d_in[0];
  const int*   ei = (const int*)d_in[1];
  const float* W1 = (const float*)d_in[2];
  const float* b1 = (const float*)d_in[3];
  const float* W2 = (const float*)d_in[4];
  const float* b2 = (const float*)d_in[5];
  const float* gw = (const float*)d_in[6];
  const float* gb = (const float*)d_in[7];
  const float* lw = (const float*)d_in[8];
  float* out = (float*)d_out;

  int n = in_sizes[0] / IN_DIM;
  int E = in_sizes[1] / 2;
  const int* src  = ei;
  const int* dstp = ei + E;

  // workspace layout (all 4B elements, 16B-aligned chunks)
  size_t n4 = ((size_t)n + 3) & ~(size_t)3;
  size_t np4 = ((size_t)n + 1 + 3) & ~(size_t)3;
  size_t E4 = ((size_t)E + 3) & ~(size_t)3;
  char* w = (char*)d_ws;
  unsigned int* deg = (unsigned int*)w;                w += n4 * 4;
  float* dinv       = (float*)w;                       w += n4 * 4;
  int* off          = (int*)w;                         w += np4 * 4;
  unsigned int* cur = (unsigned int*)w;                w += n4 * 4;
  int* csr_src      = (int*)w;                         w += E4 * 4;
  float* csr_norm   = (float*)w;                       w += E4 * 4;
  float* bufA       = (float*)w;                       w += (size_t)n4 * H1 * 4;
  float* bufB       = (float*)w;

  int gn = (n + 255) / 256;
  int gE = (E + 255) / 256;

  // degree + CSR build
  k_init_deg<<<gn, 256, 0, stream>>>(deg, n);
  k_zero_u32<<<gn, 256, 0, stream>>>(cur, n);
  k_count_deg<<<gE, 256, 0, stream>>>(dstp, deg, E);
  k_dinv<<<gn, 256, 0, stream>>>(deg, dinv, n);
  k_scan<<<1, 1024, 0, stream>>>(deg, off, n);
  k_fill<<<gE, 256, 0, stream>>>(src, dstp, dinv, off, cur, csr_src, csr_norm, E);

  // layer 1: project then gather-aggregate (bias+relu fused)
  k_proj1<<<(n + 15) / 16, 256, 0, stream>>>((const float4*)x, W1, bufA, n);
  k_agg64<<<(n * 64 + 255) / 256, 256, 0, stream>>>(bufA, dinv, off, csr_src, csr_norm, b1, bufB, n);

  // layer 2
  k_proj2<<<(n + 31) / 32, 256, 0, stream>>>(bufB, W2, bufA, n);
  k_agg32<<<(n * 64 + 255) / 256, 256, 0, stream>>>(bufA, dinv, off, csr_src, csr_norm, bufB, n);

  // tree head
  k_tree<<<(n + 7) / 8, 256, 0, stream>>>(bufB, b2, gw, gb, lw, out, n);
}

// Round 3
// 1043.802 us; speedup vs baseline: 4.4129x; 1.2879x over previous
//
#include <hip/hip_runtime.h>
#include <math.h>

#define IN_DIM 128
#define H1 64
#define H2 32
#define NC 8

// ---------------- degree / CSR prep ----------------

__global__ void k_init(unsigned int* deg, unsigned int* cur, int n) {
  int i = blockIdx.x * 256 + threadIdx.x;
  if (i < n) { deg[i] = 1u; cur[i] = 0u; }  // deg starts at 1 (self-loop)
}

__global__ void k_count_deg(const int* __restrict__ dst, unsigned int* deg, int E) {
  int i = blockIdx.x * 256 + threadIdx.x;
  if (i < E) atomicAdd(&deg[dst[i]], 1u);
}

// single-block exclusive scan of (deg-1); also emits dinv = rsqrt(deg)
__global__ __launch_bounds__(1024) void k_scan(const unsigned int* __restrict__ deg,
                                               int* __restrict__ off, float* __restrict__ dinv,
                                               int n) {
  __shared__ int part[1024];
  int tid = threadIdx.x;
  int chunk = (n + 1023) / 1024;
  int st = tid * chunk;
  int en = st + chunk; if (en > n) en = n;
  int s = 0;
  for (int i = st; i < en; ++i) s += (int)deg[i] - 1;
  part[tid] = s;
  __syncthreads();
  for (int d = 1; d < 1024; d <<= 1) {
    int v = (tid >= d) ? part[tid - d] : 0;
    __syncthreads();
    part[tid] += v;
    __syncthreads();
  }
  int base = (tid == 0) ? 0 : part[tid - 1];
  for (int i = st; i < en; ++i) {
    unsigned int dg = deg[i];
    off[i] = base; base += (int)dg - 1;
    dinv[i] = rsqrtf((float)dg);
  }
  if (tid == 1023) off[n] = part[1023];
}

// CSR fill: one packed (src, norm) entry per edge, grouped by dst
__global__ void k_fill(const int* __restrict__ src, const int* __restrict__ dst,
                       const float* __restrict__ dinv, const int* __restrict__ off,
                       unsigned int* __restrict__ cur, int2* __restrict__ csr, int E) {
  int e = blockIdx.x * 256 + threadIdx.x;
  if (e >= E) return;
  int d = dst[e], s = src[e];
  int pos = off[d] + (int)atomicAdd(&cur[d], 1u);
  int2 v; v.x = s; v.y = __float_as_int(dinv[s] * dinv[d]);
  csr[pos] = v;
}

// ---------------- projection 1: h1p = x @ W1^T  [n,128]->[n,64] ----------------

__global__ void k_proj1(const float4* __restrict__ x4, const float* __restrict__ W1,
                        float* __restrict__ h1p, int n) {
  __shared__ float xs[16][IN_DIM];
  __shared__ float wt[IN_DIM][H1 + 1];
  int tid = threadIdx.x;
  int row0 = blockIdx.x * 16;

  for (int i = tid; i < (H1 * IN_DIM / 4); i += 256) {
    float4 w = ((const float4*)W1)[i];
    int o = (i * 4) / IN_DIM;
    int k = (i * 4) % IN_DIM;
    wt[k + 0][o] = w.x; wt[k + 1][o] = w.y; wt[k + 2][o] = w.z; wt[k + 3][o] = w.w;
  }
  for (int i = tid; i < 16 * IN_DIM / 4; i += 256) {
    int r = (i * 4) / IN_DIM, k = (i * 4) % IN_DIM;
    int row = row0 + r;
    if (row < n)
      *((float4*)&xs[r][k]) = x4[(size_t)row * (IN_DIM / 4) + k / 4];
  }
  __syncthreads();

  int o = tid & 63, rq = tid >> 6;
  float a0 = 0.f, a1 = 0.f, a2 = 0.f, a3 = 0.f;
  for (int k = 0; k < IN_DIM; ++k) {
    float w = wt[k][o];
    a0 += xs[rq * 4 + 0][k] * w;
    a1 += xs[rq * 4 + 1][k] * w;
    a2 += xs[rq * 4 + 2][k] * w;
    a3 += xs[rq * 4 + 3][k] * w;
  }
  int r = row0 + rq * 4;
  if (r + 0 < n) h1p[(size_t)(r + 0) * H1 + o] = a0;
  if (r + 1 < n) h1p[(size_t)(r + 1) * H1 + o] = a1;
  if (r + 2 < n) h1p[(size_t)(r + 2) * H1 + o] = a2;
  if (r + 3 < n) h1p[(size_t)(r + 3) * H1 + o] = a3;
}

// ---------------- fused: layer-1 gather-agg + bias + relu + proj2 ----------------
// 4 waves/block, one node per wave; lane = feature (64). Epilogue applies W2^T
// in-wave via LDS, writing only h2p [n,32].

__global__ __launch_bounds__(256) void k_agg64_proj2(
    const float* __restrict__ hp, const float* __restrict__ dinv,
    const int* __restrict__ off, const int2* __restrict__ csr,
    const float* __restrict__ b1, const float* __restrict__ W2,
    float* __restrict__ h2p, int n) {
  __shared__ float wt[H1][H2 + 1];   // W2 transposed: wt[k][o]
  __shared__ float rows[4][H1];      // relu(out1) row per wave
  int tid = threadIdx.x;

  for (int i = tid; i < H2 * H1 / 4; i += 256) {
    float4 w = ((const float4*)W2)[i];
    int o = (i * 4) / H1, k = (i * 4) % H1;
    wt[k + 0][o] = w.x; wt[k + 1][o] = w.y; wt[k + 2][o] = w.z; wt[k + 3][o] = w.w;
  }

  int wv = tid >> 6, lane = tid & 63;
  int wid0 = blockIdx.x * 4 + wv;
  int wid = wid0 < n ? wid0 : n - 1;   // clamp so all waves reach barriers
  float d = dinv[wid];
  float acc = d * d * hp[(size_t)wid * H1 + lane];
  int r0 = off[wid], r1 = off[wid + 1];
  int i = r0;
  for (; i + 1 < r1; i += 2) {
    int2 e0 = csr[i], e1 = csr[i + 1];
    float v0 = hp[(size_t)e0.x * H1 + lane];
    float v1 = hp[(size_t)e1.x * H1 + lane];
    acc += __int_as_float(e0.y) * v0;
    acc += __int_as_float(e1.y) * v1;
  }
  if (i < r1) {
    int2 e = csr[i];
    acc += __int_as_float(e.y) * hp[(size_t)e.x * H1 + lane];
  }
  rows[wv][lane] = fmaxf(acc + b1[lane], 0.f);
  __syncthreads();

  // proj2: half-wave split over k, 32 outputs per node
  int o = lane & 31, half = lane >> 5;
  float a = 0.f;
#pragma unroll
  for (int k = 0; k < 32; ++k) {
    int kk = half * 32 + k;
    a += rows[wv][kk] * wt[kk][o];
  }
  a += __shfl_down(a, 32, 64);
  if (half == 0 && wid0 < n) h2p[(size_t)wid0 * H2 + o] = a;
}

// ---------------- fused: layer-2 gather-agg + b2 + gates + leaf ----------------
// 4 waves/block, one node per wave; lanes 0-31 even edges, 32-63 odd.

__global__ __launch_bounds__(256) void k_agg32_tree(
    const float* __restrict__ hp, const float* __restrict__ dinv,
    const int* __restrict__ off, const int2* __restrict__ csr,
    const float* __restrict__ b2, const float* __restrict__ gate_w,
    const float* __restrict__ gate_b, const float* __restrict__ leaf_w,
    float* __restrict__ out, int n) {
  __shared__ float gwt[H2][H2 + 1];  // gate_w transposed: gwt[k][j]
  __shared__ float lws[H2][NC + 1];
  __shared__ float rowh[4][H2];
  __shared__ float rowg[4][H2];
  int tid = threadIdx.x;

  {
    int i = tid;  // H2*H2/4 == 256: exactly one float4 per thread
    float4 w = ((const float4*)gate_w)[i];
    int j = (i * 4) / H2, k = (i * 4) % H2;
    gwt[k + 0][j] = w.x; gwt[k + 1][j] = w.y; gwt[k + 2][j] = w.z; gwt[k + 3][j] = w.w;
  }
  lws[tid >> 3][tid & 7] = leaf_w[tid];  // H2*NC == 256

  int wv = tid >> 6, lane = tid & 63;
  int wid0 = blockIdx.x * 4 + wv;
  int wid = wid0 < n ? wid0 : n - 1;
  int half = lane >> 5, f = lane & 31;
  float d = dinv[wid];
  float acc = (half == 0) ? d * d * hp[(size_t)wid * H2 + f] : 0.f;
  int r0 = off[wid], r1 = off[wid + 1];
  for (int i = r0 + half; i < r1; i += 2) {
    int2 e = csr[i];
    acc += __int_as_float(e.y) * hp[(size_t)e.x * H2 + f];
  }
  acc += __shfl_down(acc, 32, 64);
  if (half == 0) rowh[wv][f] = acc + b2[f];
  __syncthreads();

  // gates: j = f, half-wave split over k (16 each)
  float g = 0.f;
#pragma unroll
  for (int k = 0; k < 16; ++k) {
    int kk = half * 16 + k;
    g += rowh[wv][kk] * gwt[kk][f];
  }
  g += __shfl_down(g, 32, 64);
  if (half == 0) rowg[wv][f] = 1.0f / (1.0f + __expf(-(g + gate_b[f])));
  __syncthreads();

  // leaf: 8 groups of 8 lanes; group gi covers j = gi*4..gi*4+3, c = lane&7
  int c = lane & 7, gi = lane >> 3;
  float a = 0.f;
#pragma unroll
  for (int j4 = 0; j4 < 4; ++j4) {
    int jj = gi * 4 + j4;
    a += rowg[wv][jj] * lws[jj][c];
  }
  a += __shfl_down(a, 32, 64);
  a += __shfl_down(a, 16, 64);
  a += __shfl_down(a, 8, 64);
  if (lane < 8 && wid0 < n) out[(size_t)wid0 * NC + lane] = a;
}

// ---------------- host ----------------

extern "C" void kernel_launch(void* const* d_in, const int* in_sizes, int n_in,
                              void* d_out, int out_size, void* d_ws, size_t ws_size,
                              hipStream_t stream) {
  const float* x  = (const float*)d_in[0];
  const int*   ei = (const int*)d_in[1];
  const float* W1 = (const float*)d_in[2];
  const float* b1 = (const float*)d_in[3];
  const float* W2 = (const float*)d_in[4];
  const float* b2 = (const float*)d_in[5];
  const float* gw = (const float*)d_in[6];
  const float* gb = (const float*)d_in[7];
  const float* lw = (const float*)d_in[8];
  float* out = (float*)d_out;

  int n = in_sizes[0] / IN_DIM;
  int E = in_sizes[1] / 2;
  const int* src  = ei;
  const int* dstp = ei + E;

  // workspace layout (csr first for 8B alignment)
  size_t n4  = ((size_t)n + 3) & ~(size_t)3;
  size_t np4 = ((size_t)n + 1 + 3) & ~(size_t)3;
  char* w = (char*)d_ws;
  int2* csr         = (int2*)w;           w += (size_t)E * 8;
  unsigned int* deg = (unsigned int*)w;   w += n4 * 4;
  unsigned int* cur = (unsigned int*)w;   w += n4 * 4;
  float* dinv       = (float*)w;          w += n4 * 4;
  int* off          = (int*)w;            w += np4 * 4;
  float* bufA       = (float*)w;          w += n4 * (size_t)H1 * 4;  // h1p
  float* bufB       = (float*)w;                                     // h2p

  int gn = (n + 255) / 256;
  int gE = (E + 255) / 256;
  int gw4 = (n + 3) / 4;  // 4 nodes per 256-thread block

  k_init<<<gn, 256, 0, stream>>>(deg, cur, n);
  k_count_deg<<<gE, 256, 0, stream>>>(dstp, deg, E);
  k_scan<<<1, 1024, 0, stream>>>(deg, off, dinv, n);
  k_fill<<<gE, 256, 0, stream>>>(src, dstp, dinv, off, cur, csr, E);

  k_proj1<<<(n + 15) / 16, 256, 0, stream>>>((const float4*)x, W1, bufA, n);
  k_agg64_proj2<<<gw4, 256, 0, stream>>>(bufA, dinv, off, csr, b1, W2, bufB, n);
  k_agg32_tree<<<gw4, 256, 0, stream>>>(bufB, dinv, off, csr, b2, gw, gb, lw, out, n);
}

// Round 4
// 830.587 us; speedup vs baseline: 5.5457x; 1.2567x over previous
//
#include <hip/hip_runtime.h>
#include <math.h>

#define IN_DIM 128
#define H1 64
#define H2 32
#define NC 8
#define SCAN_CH 1024  // elements per scan block (256 threads x 4)

// ---------------- degree / CSR prep ----------------

__global__ void k_init(unsigned int* deg, unsigned int* cur, int n) {
  int i = blockIdx.x * 256 + threadIdx.x;
  if (i < n) { deg[i] = 1u; cur[i] = 0u; }  // deg starts at 1 (self-loop)
}

__global__ void k_count_deg(const int* __restrict__ dst, unsigned int* deg, int E) {
  int i = blockIdx.x * 256 + threadIdx.x;
  if (i < E) atomicAdd(&deg[dst[i]], 1u);
}

// ---- 3-phase multi-block exclusive scan of (deg-1), fused dinv emit ----

__global__ __launch_bounds__(256) void k_scan1(const unsigned int* __restrict__ deg,
                                               float* __restrict__ dinv,
                                               int* __restrict__ bsum, int n) {
  int b = blockIdx.x, tid = threadIdx.x;
  int i0 = b * SCAN_CH + tid * 4;
  int s = 0;
  if (i0 + 3 < n) {
    uint4 d = *(const uint4*)(deg + i0);
    s = (int)(d.x + d.y + d.z + d.w) - 4;
    float4 dv;
    dv.x = rsqrtf((float)d.x); dv.y = rsqrtf((float)d.y);
    dv.z = rsqrtf((float)d.z); dv.w = rsqrtf((float)d.w);
    *(float4*)(dinv + i0) = dv;
  } else {
    for (int i = i0; i < n; ++i) {
      unsigned int dg = deg[i];
      s += (int)dg - 1;
      dinv[i] = rsqrtf((float)dg);
    }
  }
  __shared__ int red[256];
  red[tid] = s;
  __syncthreads();
  for (int d = 128; d > 0; d >>= 1) {
    if (tid < d) red[tid] += red[tid + d];
    __syncthreads();
  }
  if (tid == 0) bsum[b] = red[0];
}

__global__ __launch_bounds__(256) void k_scan2(const int* __restrict__ bsum,
                                               int* __restrict__ bbase,
                                               int* __restrict__ off, int nb, int n) {
  __shared__ int part[256];
  int tid = threadIdx.x;
  int chunk = (nb + 255) / 256;
  int st = tid * chunk, en = st + chunk; if (en > nb) en = nb;
  int s = 0;
  for (int i = st; i < en; ++i) s += bsum[i];
  part[tid] = s;
  __syncthreads();
  for (int d = 1; d < 256; d <<= 1) {
    int t = (tid >= d) ? part[tid - d] : 0;
    __syncthreads();
    part[tid] += t;
    __syncthreads();
  }
  int base = (tid == 0) ? 0 : part[tid - 1];
  for (int i = st; i < en; ++i) { bbase[i] = base; base += bsum[i]; }
  if (tid == 255) off[n] = part[255];
}

__global__ __launch_bounds__(256) void k_scan3(const unsigned int* __restrict__ deg,
                                               const int* __restrict__ bbase,
                                               int* __restrict__ off, int n) {
  int b = blockIdx.x, tid = threadIdx.x;
  int i0 = b * SCAN_CH + tid * 4;
  int e0 = 0, e1 = 0, e2 = 0, e3 = 0;
  if (i0 + 3 < n) {
    uint4 d = *(const uint4*)(deg + i0);
    e0 = (int)d.x - 1; e1 = (int)d.y - 1; e2 = (int)d.z - 1; e3 = (int)d.w - 1;
  } else {
    if (i0 + 0 < n) e0 = (int)deg[i0 + 0] - 1;
    if (i0 + 1 < n) e1 = (int)deg[i0 + 1] - 1;
    if (i0 + 2 < n) e2 = (int)deg[i0 + 2] - 1;
    if (i0 + 3 < n) e3 = (int)deg[i0 + 3] - 1;
  }
  __shared__ int part[256];
  part[tid] = e0 + e1 + e2 + e3;
  __syncthreads();
  for (int d = 1; d < 256; d <<= 1) {
    int t = (tid >= d) ? part[tid - d] : 0;
    __syncthreads();
    part[tid] += t;
    __syncthreads();
  }
  int base = bbase[b] + ((tid == 0) ? 0 : part[tid - 1]);
  int o0 = base, o1 = o0 + e0, o2 = o1 + e1, o3 = o2 + e2;
  if (i0 + 3 < n) {
    int4 o; o.x = o0; o.y = o1; o.z = o2; o.w = o3;
    *(int4*)(off + i0) = o;
  } else {
    if (i0 + 0 < n) off[i0 + 0] = o0;
    if (i0 + 1 < n) off[i0 + 1] = o1;
    if (i0 + 2 < n) off[i0 + 2] = o2;
    if (i0 + 3 < n) off[i0 + 3] = o3;
  }
}

// CSR fill: one packed (src, norm) entry per edge, grouped by dst
__global__ void k_fill(const int* __restrict__ src, const int* __restrict__ dst,
                       const float* __restrict__ dinv, const int* __restrict__ off,
                       unsigned int* __restrict__ cur, int2* __restrict__ csr, int E) {
  int e = blockIdx.x * 256 + threadIdx.x;
  if (e >= E) return;
  int d = dst[e], s = src[e];
  int pos = off[d] + (int)atomicAdd(&cur[d], 1u);
  int2 v; v.x = s; v.y = __float_as_int(dinv[s] * dinv[d]);
  csr[pos] = v;
}

// ---------------- projection 1: h1p = x @ W1^T  [n,128]->[n,64] ----------------

__global__ void k_proj1(const float4* __restrict__ x4, const float* __restrict__ W1,
                        float* __restrict__ h1p, int n) {
  __shared__ float xs[16][IN_DIM];
  __shared__ float wt[IN_DIM][H1 + 1];
  int tid = threadIdx.x;
  int row0 = blockIdx.x * 16;

  for (int i = tid; i < (H1 * IN_DIM / 4); i += 256) {
    float4 w = ((const float4*)W1)[i];
    int o = (i * 4) / IN_DIM;
    int k = (i * 4) % IN_DIM;
    wt[k + 0][o] = w.x; wt[k + 1][o] = w.y; wt[k + 2][o] = w.z; wt[k + 3][o] = w.w;
  }
  for (int i = tid; i < 16 * IN_DIM / 4; i += 256) {
    int r = (i * 4) / IN_DIM, k = (i * 4) % IN_DIM;
    int row = row0 + r;
    if (row < n)
      *((float4*)&xs[r][k]) = x4[(size_t)row * (IN_DIM / 4) + k / 4];
  }
  __syncthreads();

  int o = tid & 63, rq = tid >> 6;
  float a0 = 0.f, a1 = 0.f, a2 = 0.f, a3 = 0.f;
  for (int k = 0; k < IN_DIM; ++k) {
    float w = wt[k][o];
    a0 += xs[rq * 4 + 0][k] * w;
    a1 += xs[rq * 4 + 1][k] * w;
    a2 += xs[rq * 4 + 2][k] * w;
    a3 += xs[rq * 4 + 3][k] * w;
  }
  int r = row0 + rq * 4;
  if (r + 0 < n) h1p[(size_t)(r + 0) * H1 + o] = a0;
  if (r + 1 < n) h1p[(size_t)(r + 1) * H1 + o] = a1;
  if (r + 2 < n) h1p[(size_t)(r + 2) * H1 + o] = a2;
  if (r + 3 < n) h1p[(size_t)(r + 3) * H1 + o] = a3;
}

// ---------------- fused: layer-1 gather-agg + bias + relu + proj2 ----------------

__global__ __launch_bounds__(256) void k_agg64_proj2(
    const float* __restrict__ hp, const float* __restrict__ dinv,
    const int* __restrict__ off, const int2* __restrict__ csr,
    const float* __restrict__ b1, const float* __restrict__ W2,
    float* __restrict__ h2p, int n) {
  __shared__ float wt[H1][H2 + 1];   // W2 transposed: wt[k][o]
  __shared__ float rows[4][H1];      // relu(out1) row per wave
  int tid = threadIdx.x;

  for (int i = tid; i < H2 * H1 / 4; i += 256) {
    float4 w = ((const float4*)W2)[i];
    int o = (i * 4) / H1, k = (i * 4) % H1;
    wt[k + 0][o] = w.x; wt[k + 1][o] = w.y; wt[k + 2][o] = w.z; wt[k + 3][o] = w.w;
  }

  int wv = tid >> 6, lane = tid & 63;
  int wid0 = blockIdx.x * 4 + wv;
  int wid = wid0 < n ? wid0 : n - 1;   // clamp so all waves reach barriers
  float d = dinv[wid];
  float acc = d * d * hp[(size_t)wid * H1 + lane];
  int r0 = off[wid], r1 = off[wid + 1];
  int i = r0;
  for (; i + 1 < r1; i += 2) {
    int2 e0 = csr[i], e1 = csr[i + 1];
    float v0 = hp[(size_t)e0.x * H1 + lane];
    float v1 = hp[(size_t)e1.x * H1 + lane];
    acc += __int_as_float(e0.y) * v0;
    acc += __int_as_float(e1.y) * v1;
  }
  if (i < r1) {
    int2 e = csr[i];
    acc += __int_as_float(e.y) * hp[(size_t)e.x * H1 + lane];
  }
  rows[wv][lane] = fmaxf(acc + b1[lane], 0.f);
  __syncthreads();

  int o = lane & 31, half = lane >> 5;
  float a = 0.f;
#pragma unroll
  for (int k = 0; k < 32; ++k) {
    int kk = half * 32 + k;
    a += rows[wv][kk] * wt[kk][o];
  }
  a += __shfl_down(a, 32, 64);
  if (half == 0 && wid0 < n) h2p[(size_t)wid0 * H2 + o] = a;
}

// ---------------- fused: layer-2 gather-agg + b2 + gates + leaf ----------------

__global__ __launch_bounds__(256) void k_agg32_tree(
    const float* __restrict__ hp, const float* __restrict__ dinv,
    const int* __restrict__ off, const int2* __restrict__ csr,
    const float* __restrict__ b2, const float* __restrict__ gate_w,
    const float* __restrict__ gate_b, const float* __restrict__ leaf_w,
    float* __restrict__ out, int n) {
  __shared__ float gwt[H2][H2 + 1];  // gate_w transposed: gwt[k][j]
  __shared__ float lws[H2][NC + 1];
  __shared__ float rowh[4][H2];
  __shared__ float rowg[4][H2];
  int tid = threadIdx.x;

  {
    int i = tid;  // H2*H2/4 == 256
    float4 w = ((const float4*)gate_w)[i];
    int j = (i * 4) / H2, k = (i * 4) % H2;
    gwt[k + 0][j] = w.x; gwt[k + 1][j] = w.y; gwt[k + 2][j] = w.z; gwt[k + 3][j] = w.w;
  }
  lws[tid >> 3][tid & 7] = leaf_w[tid];  // H2*NC == 256

  int wv = tid >> 6, lane = tid & 63;
  int wid0 = blockIdx.x * 4 + wv;
  int wid = wid0 < n ? wid0 : n - 1;
  int half = lane >> 5, f = lane & 31;
  float d = dinv[wid];
  float acc = (half == 0) ? d * d * hp[(size_t)wid * H2 + f] : 0.f;
  int r0 = off[wid], r1 = off[wid + 1];
  for (int i = r0 + half; i < r1; i += 2) {
    int2 e = csr[i];
    acc += __int_as_float(e.y) * hp[(size_t)e.x * H2 + f];
  }
  acc += __shfl_down(acc, 32, 64);
  if (half == 0) rowh[wv][f] = acc + b2[f];
  __syncthreads();

  float g = 0.f;
#pragma unroll
  for (int k = 0; k < 16; ++k) {
    int kk = half * 16 + k;
    g += rowh[wv][kk] * gwt[kk][f];
  }
  g += __shfl_down(g, 32, 64);
  if (half == 0) rowg[wv][f] = 1.0f / (1.0f + __expf(-(g + gate_b[f])));
  __syncthreads();

  int c = lane & 7, gi = lane >> 3;
  float a = 0.f;
#pragma unroll
  for (int j4 = 0; j4 < 4; ++j4) {
    int jj = gi * 4 + j4;
    a += rowg[wv][jj] * lws[jj][c];
  }
  a += __shfl_down(a, 32, 64);
  a += __shfl_down(a, 16, 64);
  a += __shfl_down(a, 8, 64);
  if (lane < 8 && wid0 < n) out[(size_t)wid0 * NC + lane] = a;
}

// ---------------- host ----------------

extern "C" void kernel_launch(void* const* d_in, const int* in_sizes, int n_in,
                              void* d_out, int out_size, void* d_ws, size_t ws_size,
                              hipStream_t stream) {
  const float* x  = (const float*)d_in[0];
  const int*   ei = (const int*)d_in[1];
  const float* W1 = (const float*)d_in[2];
  const float* b1 = (const float*)d_in[3];
  const float* W2 = (const float*)d_in[4];
  const float* b2 = (const float*)d_in[5];
  const float* gw = (const float*)d_in[6];
  const float* gb = (const float*)d_in[7];
  const float* lw = (const float*)d_in[8];
  float* out = (float*)d_out;

  int n = in_sizes[0] / IN_DIM;
  int E = in_sizes[1] / 2;
  const int* src  = ei;
  const int* dstp = ei + E;

  int nb = (n + SCAN_CH - 1) / SCAN_CH;

  // workspace layout (csr first for 8B alignment)
  size_t n4  = ((size_t)n + 3) & ~(size_t)3;
  size_t np4 = ((size_t)n + 1 + 3) & ~(size_t)3;
  size_t nb4 = ((size_t)nb + 3) & ~(size_t)3;
  char* w = (char*)d_ws;
  int2* csr         = (int2*)w;           w += (size_t)E * 8;
  unsigned int* deg = (unsigned int*)w;   w += n4 * 4;
  unsigned int* cur = (unsigned int*)w;   w += n4 * 4;
  float* dinv       = (float*)w;          w += n4 * 4;
  int* off          = (int*)w;            w += np4 * 4;
  int* bsum         = (int*)w;            w += nb4 * 4;
  int* bbase        = (int*)w;            w += nb4 * 4;
  float* bufA       = (float*)w;          w += n4 * (size_t)H1 * 4;  // h1p
  float* bufB       = (float*)w;                                     // h2p

  int gn = (n + 255) / 256;
  int gE = (E + 255) / 256;
  int gw4 = (n + 3) / 4;  // 4 nodes per 256-thread block

  k_init<<<gn, 256, 0, stream>>>(deg, cur, n);
  k_count_deg<<<gE, 256, 0, stream>>>(dstp, deg, E);
  k_scan1<<<nb, 256, 0, stream>>>(deg, dinv, bsum, n);
  k_scan2<<<1, 256, 0, stream>>>(bsum, bbase, off, nb, n);
  k_scan3<<<nb, 256, 0, stream>>>(deg, bbase, off, n);
  k_fill<<<gE, 256, 0, stream>>>(src, dstp, dinv, off, cur, csr, E);

  k_proj1<<<(n + 15) / 16, 256, 0, stream>>>((const float4*)x, W1, bufA, n);
  k_agg64_proj2<<<gw4, 256, 0, stream>>>(bufA, dinv, off, csr, b1, W2, bufB, n);
  k_agg32_tree<<<gw4, 256, 0, stream>>>(bufB, dinv, off, csr, b2, gw, gb, lw, out, n);
}

// Round 5
// 809.218 us; speedup vs baseline: 5.6921x; 1.0264x over previous
//
#include <hip/hip_runtime.h>
#include <math.h>

#define IN_DIM 128
#define H1 64
#define H2 32
#define NC 8
#define SCAN_CH 1024  // elements per scan block (256 threads x 4)

typedef unsigned int u32;

__device__ __forceinline__ float bf_lo(u32 u) { return __uint_as_float(u << 16); }
__device__ __forceinline__ float bf_hi(u32 u) { return __uint_as_float(u & 0xffff0000u); }
__device__ __forceinline__ unsigned short f2b(float f) {  // RNE float->bf16
  u32 u = __float_as_uint(f);
  u += 0x7fffu + ((u >> 16) & 1u);
  return (unsigned short)(u >> 16);
}

// ---------------- degree / CSR prep ----------------

__global__ void k_init(unsigned int* deg, int n) {
  int i = blockIdx.x * 256 + threadIdx.x;
  if (i < n) deg[i] = 1u;  // self-loop
}

__global__ void k_count_deg(const int* __restrict__ dst, unsigned int* deg, int E) {
  int i = (blockIdx.x * 256 + threadIdx.x) * 4;
  if (i + 3 < E) {
    int4 d = *(const int4*)(dst + i);
    atomicAdd(&deg[d.x], 1u);
    atomicAdd(&deg[d.y], 1u);
    atomicAdd(&deg[d.z], 1u);
    atomicAdd(&deg[d.w], 1u);
  } else {
    for (int j = i; j < E; ++j) atomicAdd(&deg[dst[j]], 1u);
  }
}

// ---- 3-phase multi-block exclusive scan of (deg-1), fused dinv emit ----

__global__ __launch_bounds__(256) void k_scan1(const unsigned int* __restrict__ deg,
                                               float* __restrict__ dinv,
                                               int* __restrict__ bsum, int n) {
  int b = blockIdx.x, tid = threadIdx.x;
  int i0 = b * SCAN_CH + tid * 4;
  int s = 0;
  if (i0 + 3 < n) {
    uint4 d = *(const uint4*)(deg + i0);
    s = (int)(d.x + d.y + d.z + d.w) - 4;
    float4 dv;
    dv.x = rsqrtf((float)d.x); dv.y = rsqrtf((float)d.y);
    dv.z = rsqrtf((float)d.z); dv.w = rsqrtf((float)d.w);
    *(float4*)(dinv + i0) = dv;
  } else {
    for (int i = i0; i < n; ++i) {
      unsigned int dg = deg[i];
      s += (int)dg - 1;
      dinv[i] = rsqrtf((float)dg);
    }
  }
  __shared__ int red[256];
  red[tid] = s;
  __syncthreads();
  for (int d = 128; d > 0; d >>= 1) {
    if (tid < d) red[tid] += red[tid + d];
    __syncthreads();
  }
  if (tid == 0) bsum[b] = red[0];
}

__global__ __launch_bounds__(256) void k_scan2(const int* __restrict__ bsum,
                                               int* __restrict__ bbase,
                                               int* __restrict__ off, int nb, int n) {
  __shared__ int part[256];
  int tid = threadIdx.x;
  int chunk = (nb + 255) / 256;
  int st = tid * chunk, en = st + chunk; if (en > nb) en = nb;
  int s = 0;
  for (int i = st; i < en; ++i) s += bsum[i];
  part[tid] = s;
  __syncthreads();
  for (int d = 1; d < 256; d <<= 1) {
    int t = (tid >= d) ? part[tid - d] : 0;
    __syncthreads();
    part[tid] += t;
    __syncthreads();
  }
  int base = (tid == 0) ? 0 : part[tid - 1];
  for (int i = st; i < en; ++i) { bbase[i] = base; base += bsum[i]; }
  if (tid == 255) off[n] = part[255];
}

__global__ __launch_bounds__(256) void k_scan3(const unsigned int* __restrict__ deg,
                                               const int* __restrict__ bbase,
                                               int* __restrict__ off,
                                               unsigned int* __restrict__ cur, int n) {
  int b = blockIdx.x, tid = threadIdx.x;
  int i0 = b * SCAN_CH + tid * 4;
  int e0 = 0, e1 = 0, e2 = 0, e3 = 0;
  if (i0 + 3 < n) {
    uint4 d = *(const uint4*)(deg + i0);
    e0 = (int)d.x - 1; e1 = (int)d.y - 1; e2 = (int)d.z - 1; e3 = (int)d.w - 1;
    uint4 z; z.x = z.y = z.z = z.w = 0u;
    *(uint4*)(cur + i0) = z;
  } else {
    if (i0 + 0 < n) { e0 = (int)deg[i0 + 0] - 1; cur[i0 + 0] = 0u; }
    if (i0 + 1 < n) { e1 = (int)deg[i0 + 1] - 1; cur[i0 + 1] = 0u; }
    if (i0 + 2 < n) { e2 = (int)deg[i0 + 2] - 1; cur[i0 + 2] = 0u; }
    if (i0 + 3 < n) { e3 = (int)deg[i0 + 3] - 1; cur[i0 + 3] = 0u; }
  }
  __shared__ int part[256];
  part[tid] = e0 + e1 + e2 + e3;
  __syncthreads();
  for (int d = 1; d < 256; d <<= 1) {
    int t = (tid >= d) ? part[tid - d] : 0;
    __syncthreads();
    part[tid] += t;
    __syncthreads();
  }
  int base = bbase[b] + ((tid == 0) ? 0 : part[tid - 1]);
  int o0 = base, o1 = o0 + e0, o2 = o1 + e1, o3 = o2 + e2;
  if (i0 + 3 < n) {
    int4 o; o.x = o0; o.y = o1; o.z = o2; o.w = o3;
    *(int4*)(off + i0) = o;
  } else {
    if (i0 + 0 < n) off[i0 + 0] = o0;
    if (i0 + 1 < n) off[i0 + 1] = o1;
    if (i0 + 2 < n) off[i0 + 2] = o2;
    if (i0 + 3 < n) off[i0 + 3] = o3;
  }
}

// CSR fill: src index only, grouped by dst (norm folded into feature tables)
__global__ void k_fill(const int* __restrict__ src, const int* __restrict__ dst,
                       const int* __restrict__ off, unsigned int* __restrict__ cur,
                       int* __restrict__ csr, int E) {
  int i = (blockIdx.x * 256 + threadIdx.x) * 4;
  if (i + 3 < E) {
    int4 s4 = *(const int4*)(src + i);
    int4 d4 = *(const int4*)(dst + i);
    int p0 = off[d4.x] + (int)atomicAdd(&cur[d4.x], 1u);
    int p1 = off[d4.y] + (int)atomicAdd(&cur[d4.y], 1u);
    int p2 = off[d4.z] + (int)atomicAdd(&cur[d4.z], 1u);
    int p3 = off[d4.w] + (int)atomicAdd(&cur[d4.w], 1u);
    csr[p0] = s4.x; csr[p1] = s4.y; csr[p2] = s4.z; csr[p3] = s4.w;
  } else {
    for (int j = i; j < E; ++j) {
      int d = dst[j];
      int pos = off[d] + (int)atomicAdd(&cur[d], 1u);
      csr[pos] = src[j];
    }
  }
}

// ---------------- projection 1: h1p = bf16(dinv * (x @ W1^T))  [n,128]->[n,64] ----------------

__global__ void k_proj1(const float4* __restrict__ x4, const float* __restrict__ W1,
                        const float* __restrict__ dinv,
                        unsigned short* __restrict__ h1p, int n) {
  __shared__ float xs[16][IN_DIM];
  __shared__ float wt[IN_DIM][H1 + 1];
  int tid = threadIdx.x;
  int row0 = blockIdx.x * 16;

  for (int i = tid; i < (H1 * IN_DIM / 4); i += 256) {
    float4 w = ((const float4*)W1)[i];
    int o = (i * 4) / IN_DIM;
    int k = (i * 4) % IN_DIM;
    wt[k + 0][o] = w.x; wt[k + 1][o] = w.y; wt[k + 2][o] = w.z; wt[k + 3][o] = w.w;
  }
  for (int i = tid; i < 16 * IN_DIM / 4; i += 256) {
    int r = (i * 4) / IN_DIM, k = (i * 4) % IN_DIM;
    int row = row0 + r;
    if (row < n)
      *((float4*)&xs[r][k]) = x4[(size_t)row * (IN_DIM / 4) + k / 4];
  }
  __syncthreads();

  int o = tid & 63, rq = tid >> 6;
  float a0 = 0.f, a1 = 0.f, a2 = 0.f, a3 = 0.f;
  for (int k = 0; k < IN_DIM; ++k) {
    float w = wt[k][o];
    a0 += xs[rq * 4 + 0][k] * w;
    a1 += xs[rq * 4 + 1][k] * w;
    a2 += xs[rq * 4 + 2][k] * w;
    a3 += xs[rq * 4 + 3][k] * w;
  }
  int r = row0 + rq * 4;
  if (r + 0 < n) h1p[(size_t)(r + 0) * H1 + o] = f2b(a0 * dinv[r + 0]);
  if (r + 1 < n) h1p[(size_t)(r + 1) * H1 + o] = f2b(a1 * dinv[r + 1]);
  if (r + 2 < n) h1p[(size_t)(r + 2) * H1 + o] = f2b(a2 * dinv[r + 2]);
  if (r + 3 < n) h1p[(size_t)(r + 3) * H1 + o] = f2b(a3 * dinv[r + 3]);
}

// ---------------- fused: layer-1 gather-agg + bias + relu + proj2 ----------------
// 4 waves/block, one node per wave. Half-wave split: 2 edges in flight; each
// lane loads 1 uint (2 packed bf16 feats). Table rows already scaled by dinv[src].

__global__ __launch_bounds__(256) void k_agg64_proj2(
    const u32* __restrict__ hp,    // [n][32] packed bf16x2
    const float* __restrict__ dinv,
    const int* __restrict__ off, const int* __restrict__ csr,
    const float* __restrict__ b1, const float* __restrict__ W2,
    unsigned short* __restrict__ h2p, int n) {
  __shared__ float wt[H1][H2 + 1];   // W2 transposed: wt[k][o]
  __shared__ float rows[4][H1];      // relu(out1) row per wave
  int tid = threadIdx.x;

  for (int i = tid; i < H2 * H1 / 4; i += 256) {
    float4 w = ((const float4*)W2)[i];
    int o = (i * 4) / H1, k = (i * 4) % H1;
    wt[k + 0][o] = w.x; wt[k + 1][o] = w.y; wt[k + 2][o] = w.z; wt[k + 3][o] = w.w;
  }

  int lane = tid & 63;
  int wv = __builtin_amdgcn_readfirstlane(tid >> 6);
  int wid0 = blockIdx.x * 4 + wv;
  int wid = wid0 < n ? wid0 : n - 1;   // clamp so all waves reach barriers
  int half = lane >> 5, f2 = lane & 31;

  float ax = 0.f, ay = 0.f;
  if (half == 0) {  // self term (table already has dinv[self] folded in)
    u32 u = hp[(size_t)wid * (H1 / 2) + f2];
    ax = bf_lo(u); ay = bf_hi(u);
  }
  int r0 = off[wid], r1 = off[wid + 1];
  for (int i = r0 + half; i < r1; i += 2) {
    u32 u = hp[(size_t)csr[i] * (H1 / 2) + f2];
    ax += bf_lo(u);
    ay += bf_hi(u);
  }
  ax += __shfl_down(ax, 32, 64);
  ay += __shfl_down(ay, 32, 64);
  float d = dinv[wid];
  if (half == 0) {
    float2 rv;
    rv.x = fmaxf(ax * d + b1[2 * f2 + 0], 0.f);
    rv.y = fmaxf(ay * d + b1[2 * f2 + 1], 0.f);
    *(float2*)&rows[wv][2 * f2] = rv;
  }
  __syncthreads();

  // proj2: half-wave split over k, 32 outputs per node
  int o = lane & 31;
  float a = 0.f;
#pragma unroll
  for (int k = 0; k < 32; ++k) {
    int kk = half * 32 + k;
    a += rows[wv][kk] * wt[kk][o];
  }
  a += __shfl_down(a, 32, 64);
  if (half == 0 && wid0 < n) h2p[(size_t)wid0 * H2 + o] = f2b(a * d);
}

// ---------------- fused: layer-2 gather-agg + b2 + gates + leaf ----------------
// Quarter-wave split: 4 edges in flight; each lane loads 1 uint (2 feats).

__global__ __launch_bounds__(256) void k_agg32_tree(
    const u32* __restrict__ hp,    // [n][16] packed bf16x2
    const float* __restrict__ dinv,
    const int* __restrict__ off, const int* __restrict__ csr,
    const float* __restrict__ b2, const float* __restrict__ gate_w,
    const float* __restrict__ gate_b, const float* __restrict__ leaf_w,
    float* __restrict__ out, int n) {
  __shared__ float gwt[H2][H2 + 1];  // gate_w transposed: gwt[k][j]
  __shared__ float lws[H2][NC + 1];
  __shared__ float rowh[4][H2];
  __shared__ float rowg[4][H2];
  int tid = threadIdx.x;

  {
    float4 w = ((const float4*)gate_w)[tid];  // H2*H2/4 == 256
    int j = (tid * 4) / H2, k = (tid * 4) % H2;
    gwt[k + 0][j] = w.x; gwt[k + 1][j] = w.y; gwt[k + 2][j] = w.z; gwt[k + 3][j] = w.w;
  }
  lws[tid >> 3][tid & 7] = leaf_w[tid];  // H2*NC == 256

  int lane = tid & 63;
  int wv = __builtin_amdgcn_readfirstlane(tid >> 6);
  int wid0 = blockIdx.x * 4 + wv;
  int wid = wid0 < n ? wid0 : n - 1;
  int q = lane >> 4, f2 = lane & 15;

  float ax = 0.f, ay = 0.f;
  if (q == 0) {  // self term
    u32 u = hp[(size_t)wid * (H2 / 2) + f2];
    ax = bf_lo(u); ay = bf_hi(u);
  }
  int r0 = off[wid], r1 = off[wid + 1];
  for (int i = r0 + q; i < r1; i += 4) {
    u32 u = hp[(size_t)csr[i] * (H2 / 2) + f2];
    ax += bf_lo(u);
    ay += bf_hi(u);
  }
  ax += __shfl_down(ax, 32, 64); ay += __shfl_down(ay, 32, 64);
  ax += __shfl_down(ax, 16, 64); ay += __shfl_down(ay, 16, 64);
  float d = dinv[wid];
  if (lane < 16) {
    float2 rv;
    rv.x = ax * d + b2[2 * f2 + 0];
    rv.y = ay * d + b2[2 * f2 + 1];
    *(float2*)&rowh[wv][2 * f2] = rv;
  }
  __syncthreads();

  // gates: j = f, half-wave split over k (16 each)
  int half = lane >> 5, f = lane & 31;
  float g = 0.f;
#pragma unroll
  for (int k = 0; k < 16; ++k) {
    int kk = half * 16 + k;
    g += rowh[wv][kk] * gwt[kk][f];
  }
  g += __shfl_down(g, 32, 64);
  if (half == 0) rowg[wv][f] = 1.0f / (1.0f + __expf(-(g + gate_b[f])));
  __syncthreads();

  // leaf: 8 groups of 8 lanes
  int c = lane & 7, gi = lane >> 3;
  float a = 0.f;
#pragma unroll
  for (int j4 = 0; j4 < 4; ++j4) {
    int jj = gi * 4 + j4;
    a += rowg[wv][jj] * lws[jj][c];
  }
  a += __shfl_down(a, 32, 64);
  a += __shfl_down(a, 16, 64);
  a += __shfl_down(a, 8, 64);
  if (lane < 8 && wid0 < n) out[(size_t)wid0 * NC + lane] = a;
}

// ---------------- host ----------------

extern "C" void kernel_launch(void* const* d_in, const int* in_sizes, int n_in,
                              void* d_out, int out_size, void* d_ws, size_t ws_size,
                              hipStream_t stream) {
  const float* x  = (const float*)d_in[0];
  const int*   ei = (const int*)d_in[1];
  const float* W1 = (const float*)d_in[2];
  const float* b1 = (const float*)d_in[3];
  const float* W2 = (const float*)d_in[4];
  const float* b2 = (const float*)d_in[5];
  const float* gw = (const float*)d_in[6];
  const float* gb = (const float*)d_in[7];
  const float* lw = (const float*)d_in[8];
  float* out = (float*)d_out;

  int n = in_sizes[0] / IN_DIM;
  int E = in_sizes[1] / 2;
  const int* src  = ei;
  const int* dstp = ei + E;

  int nb = (n + SCAN_CH - 1) / SCAN_CH;

  // workspace layout (16B-aligned chunks)
  size_t n4  = ((size_t)n + 3) & ~(size_t)3;
  size_t np4 = ((size_t)n + 1 + 3) & ~(size_t)3;
  size_t nb4 = ((size_t)nb + 3) & ~(size_t)3;
  size_t E4  = ((size_t)E + 3) & ~(size_t)3;
  char* w = (char*)d_ws;
  int* csr          = (int*)w;            w += E4 * 4;
  unsigned int* deg = (unsigned int*)w;   w += n4 * 4;
  unsigned int* cur = (unsigned int*)w;   w += n4 * 4;
  float* dinv       = (float*)w;          w += n4 * 4;
  int* off          = (int*)w;            w += np4 * 4;
  int* bsum         = (int*)w;            w += nb4 * 4;
  int* bbase        = (int*)w;            w += nb4 * 4;
  unsigned short* h1p = (unsigned short*)w;  w += n4 * (size_t)H1 * 2;  // bf16 [n][64]
  unsigned short* h2p = (unsigned short*)w;                             // bf16 [n][32]

  int gn  = (n + 255) / 256;
  int gE4 = ((E + 3) / 4 + 255) / 256;
  int gw4 = (n + 3) / 4;  // 4 nodes per 256-thread block

  k_init<<<gn, 256, 0, stream>>>(deg, n);
  k_count_deg<<<gE4, 256, 0, stream>>>(dstp, deg, E);
  k_scan1<<<nb, 256, 0, stream>>>(deg, dinv, bsum, n);
  k_scan2<<<1, 256, 0, stream>>>(bsum, bbase, off, nb, n);
  k_scan3<<<nb, 256, 0, stream>>>(deg, bbase, off, cur, n);
  k_fill<<<gE4, 256, 0, stream>>>(src, dstp, off, cur, csr, E);

  k_proj1<<<(n + 15) / 16, 256, 0, stream>>>((const float4*)x, W1, dinv, h1p, n);
  k_agg64_proj2<<<gw4, 256, 0, stream>>>((const u32*)h1p, dinv, off, csr, b1, W2, h2p, n);
  k_agg32_tree<<<gw4, 256, 0, stream>>>((const u32*)h2p, dinv, off, csr, b2, gw, gb, lw, out, n);
}

// Round 6
// 629.310 us; speedup vs baseline: 7.3194x; 1.2859x over previous
//
#include <hip/hip_runtime.h>
#include <math.h>

#define IN_DIM 128
#define H1 64
#define H2 32
#define NC 8
#define SCAN_CH 1024  // elements per scan block (256 threads x 4)

typedef unsigned int u32;

__device__ __forceinline__ float bf_lo(u32 u) { return __uint_as_float(u << 16); }
__device__ __forceinline__ float bf_hi(u32 u) { return __uint_as_float(u & 0xffff0000u); }
__device__ __forceinline__ unsigned short f2b(float f) {  // RNE float->bf16
  u32 u = __float_as_uint(f);
  u += 0x7fffu + ((u >> 16) & 1u);
  return (unsigned short)(u >> 16);
}

// ---------------- fused degree count + per-edge rank ----------------
// deg[] pre-zeroed; rank[e] = #earlier edges with same dst (atomic order).

__global__ void k_count_rank(const int* __restrict__ dst, unsigned int* __restrict__ deg,
                             int* __restrict__ rank, int E) {
  int i = (blockIdx.x * 256 + threadIdx.x) * 4;
  if (i + 3 < E) {
    int4 d = *(const int4*)(dst + i);
    int4 r;
    r.x = (int)atomicAdd(&deg[d.x], 1u);
    r.y = (int)atomicAdd(&deg[d.y], 1u);
    r.z = (int)atomicAdd(&deg[d.z], 1u);
    r.w = (int)atomicAdd(&deg[d.w], 1u);
    *(int4*)(rank + i) = r;
  } else {
    for (int j = i; j < E; ++j) rank[j] = (int)atomicAdd(&deg[dst[j]], 1u);
  }
}

// ---- 3-phase multi-block exclusive scan of count, fused dinv = rsqrt(count+1) ----

__global__ __launch_bounds__(256) void k_scan1(const unsigned int* __restrict__ deg,
                                               float* __restrict__ dinv,
                                               int* __restrict__ bsum, int n) {
  int b = blockIdx.x, tid = threadIdx.x;
  int i0 = b * SCAN_CH + tid * 4;
  int s = 0;
  if (i0 + 3 < n) {
    uint4 d = *(const uint4*)(deg + i0);
    s = (int)(d.x + d.y + d.z + d.w);
    float4 dv;
    dv.x = rsqrtf((float)(d.x + 1u)); dv.y = rsqrtf((float)(d.y + 1u));
    dv.z = rsqrtf((float)(d.z + 1u)); dv.w = rsqrtf((float)(d.w + 1u));
    *(float4*)(dinv + i0) = dv;
  } else {
    for (int i = i0; i < n; ++i) {
      unsigned int dg = deg[i];
      s += (int)dg;
      dinv[i] = rsqrtf((float)(dg + 1u));
    }
  }
  __shared__ int red[256];
  red[tid] = s;
  __syncthreads();
  for (int d = 128; d > 0; d >>= 1) {
    if (tid < d) red[tid] += red[tid + d];
    __syncthreads();
  }
  if (tid == 0) bsum[b] = red[0];
}

__global__ __launch_bounds__(256) void k_scan2(const int* __restrict__ bsum,
                                               int* __restrict__ bbase,
                                               int* __restrict__ off, int nb, int n) {
  __shared__ int part[256];
  int tid = threadIdx.x;
  int chunk = (nb + 255) / 256;
  int st = tid * chunk, en = st + chunk; if (en > nb) en = nb;
  int s = 0;
  for (int i = st; i < en; ++i) s += bsum[i];
  part[tid] = s;
  __syncthreads();
  for (int d = 1; d < 256; d <<= 1) {
    int t = (tid >= d) ? part[tid - d] : 0;
    __syncthreads();
    part[tid] += t;
    __syncthreads();
  }
  int base = (tid == 0) ? 0 : part[tid - 1];
  for (int i = st; i < en; ++i) { bbase[i] = base; base += bsum[i]; }
  if (tid == 255) off[n] = part[255];
}

__global__ __launch_bounds__(256) void k_scan3(const unsigned int* __restrict__ deg,
                                               const int* __restrict__ bbase,
                                               int* __restrict__ off, int n) {
  int b = blockIdx.x, tid = threadIdx.x;
  int i0 = b * SCAN_CH + tid * 4;
  int e0 = 0, e1 = 0, e2 = 0, e3 = 0;
  if (i0 + 3 < n) {
    uint4 d = *(const uint4*)(deg + i0);
    e0 = (int)d.x; e1 = (int)d.y; e2 = (int)d.z; e3 = (int)d.w;
  } else {
    if (i0 + 0 < n) e0 = (int)deg[i0 + 0];
    if (i0 + 1 < n) e1 = (int)deg[i0 + 1];
    if (i0 + 2 < n) e2 = (int)deg[i0 + 2];
    if (i0 + 3 < n) e3 = (int)deg[i0 + 3];
  }
  __shared__ int part[256];
  part[tid] = e0 + e1 + e2 + e3;
  __syncthreads();
  for (int d = 1; d < 256; d <<= 1) {
    int t = (tid >= d) ? part[tid - d] : 0;
    __syncthreads();
    part[tid] += t;
    __syncthreads();
  }
  int base = bbase[b] + ((tid == 0) ? 0 : part[tid - 1]);
  int o0 = base, o1 = o0 + e0, o2 = o1 + e1, o3 = o2 + e2;
  if (i0 + 3 < n) {
    int4 o; o.x = o0; o.y = o1; o.z = o2; o.w = o3;
    *(int4*)(off + i0) = o;
  } else {
    if (i0 + 0 < n) off[i0 + 0] = o0;
    if (i0 + 1 < n) off[i0 + 1] = o1;
    if (i0 + 2 < n) off[i0 + 2] = o2;
    if (i0 + 3 < n) off[i0 + 3] = o3;
  }
}

// ---------------- atomic-free CSR fill ----------------

__global__ void k_fill2(const int* __restrict__ src, const int* __restrict__ dst,
                        const int* __restrict__ rank, const int* __restrict__ off,
                        int* __restrict__ csr, int E) {
  int i = (blockIdx.x * 256 + threadIdx.x) * 4;
  if (i + 3 < E) {
    int4 s4 = *(const int4*)(src + i);
    int4 d4 = *(const int4*)(dst + i);
    int4 r4 = *(const int4*)(rank + i);
    csr[off[d4.x] + r4.x] = s4.x;
    csr[off[d4.y] + r4.y] = s4.y;
    csr[off[d4.z] + r4.z] = s4.z;
    csr[off[d4.w] + r4.w] = s4.w;
  } else {
    for (int j = i; j < E; ++j) csr[off[dst[j]] + rank[j]] = src[j];
  }
}

// ---------------- projection 1: h1p = bf16(dinv * (x @ W1^T))  [n,128]->[n,64] ----------------

__global__ void k_proj1(const float4* __restrict__ x4, const float* __restrict__ W1,
                        const float* __restrict__ dinv,
                        unsigned short* __restrict__ h1p, int n) {
  __shared__ float xs[16][IN_DIM];
  __shared__ float wt[IN_DIM][H1 + 1];
  int tid = threadIdx.x;
  int row0 = blockIdx.x * 16;

  for (int i = tid; i < (H1 * IN_DIM / 4); i += 256) {
    float4 w = ((const float4*)W1)[i];
    int o = (i * 4) / IN_DIM;
    int k = (i * 4) % IN_DIM;
    wt[k + 0][o] = w.x; wt[k + 1][o] = w.y; wt[k + 2][o] = w.z; wt[k + 3][o] = w.w;
  }
  for (int i = tid; i < 16 * IN_DIM / 4; i += 256) {
    int r = (i * 4) / IN_DIM, k = (i * 4) % IN_DIM;
    int row = row0 + r;
    if (row < n)
      *((float4*)&xs[r][k]) = x4[(size_t)row * (IN_DIM / 4) + k / 4];
  }
  __syncthreads();

  int o = tid & 63, rq = tid >> 6;
  float a0 = 0.f, a1 = 0.f, a2 = 0.f, a3 = 0.f;
  for (int k = 0; k < IN_DIM; ++k) {
    float w = wt[k][o];
    a0 += xs[rq * 4 + 0][k] * w;
    a1 += xs[rq * 4 + 1][k] * w;
    a2 += xs[rq * 4 + 2][k] * w;
    a3 += xs[rq * 4 + 3][k] * w;
  }
  int r = row0 + rq * 4;
  if (r + 0 < n) h1p[(size_t)(r + 0) * H1 + o] = f2b(a0 * dinv[r + 0]);
  if (r + 1 < n) h1p[(size_t)(r + 1) * H1 + o] = f2b(a1 * dinv[r + 1]);
  if (r + 2 < n) h1p[(size_t)(r + 2) * H1 + o] = f2b(a2 * dinv[r + 2]);
  if (r + 3 < n) h1p[(size_t)(r + 3) * H1 + o] = f2b(a3 * dinv[r + 3]);
}

// ---------------- fused: layer-1 gather-agg + bias + relu + proj2 ----------------

__global__ __launch_bounds__(256) void k_agg64_proj2(
    const u32* __restrict__ hp,    // [n][32] packed bf16x2
    const float* __restrict__ dinv,
    const int* __restrict__ off, const int* __restrict__ csr,
    const float* __restrict__ b1, const float* __restrict__ W2,
    unsigned short* __restrict__ h2p, int n) {
  __shared__ float wt[H1][H2 + 1];   // W2 transposed: wt[k][o]
  __shared__ float rows[4][H1];      // relu(out1) row per wave
  int tid = threadIdx.x;

  for (int i = tid; i < H2 * H1 / 4; i += 256) {
    float4 w = ((const float4*)W2)[i];
    int o = (i * 4) / H1, k = (i * 4) % H1;
    wt[k + 0][o] = w.x; wt[k + 1][o] = w.y; wt[k + 2][o] = w.z; wt[k + 3][o] = w.w;
  }

  int lane = tid & 63;
  int wv = __builtin_amdgcn_readfirstlane(tid >> 6);
  int wid0 = blockIdx.x * 4 + wv;
  int wid = wid0 < n ? wid0 : n - 1;   // clamp so all waves reach barriers
  int half = lane >> 5, f2 = lane & 31;

  float ax = 0.f, ay = 0.f;
  if (half == 0) {  // self term (table already has dinv[self] folded in)
    u32 u = hp[(size_t)wid * (H1 / 2) + f2];
    ax = bf_lo(u); ay = bf_hi(u);
  }
  int r0 = off[wid], r1 = off[wid + 1];
  for (int i = r0 + half; i < r1; i += 2) {
    u32 u = hp[(size_t)csr[i] * (H1 / 2) + f2];
    ax += bf_lo(u);
    ay += bf_hi(u);
  }
  ax += __shfl_down(ax, 32, 64);
  ay += __shfl_down(ay, 32, 64);
  float d = dinv[wid];
  if (half == 0) {
    float2 rv;
    rv.x = fmaxf(ax * d + b1[2 * f2 + 0], 0.f);
    rv.y = fmaxf(ay * d + b1[2 * f2 + 1], 0.f);
    *(float2*)&rows[wv][2 * f2] = rv;
  }
  __syncthreads();

  // proj2: half-wave split over k, 32 outputs per node
  int o = lane & 31;
  float a = 0.f;
#pragma unroll
  for (int k = 0; k < 32; ++k) {
    int kk = half * 32 + k;
    a += rows[wv][kk] * wt[kk][o];
  }
  a += __shfl_down(a, 32, 64);
  if (half == 0 && wid0 < n) h2p[(size_t)wid0 * H2 + o] = f2b(a * d);
}

// ---------------- fused: layer-2 gather-agg + b2 + gates + leaf ----------------

__global__ __launch_bounds__(256) void k_agg32_tree(
    const u32* __restrict__ hp,    // [n][16] packed bf16x2
    const float* __restrict__ dinv,
    const int* __restrict__ off, const int* __restrict__ csr,
    const float* __restrict__ b2, const float* __restrict__ gate_w,
    const float* __restrict__ gate_b, const float* __restrict__ leaf_w,
    float* __restrict__ out, int n) {
  __shared__ float gwt[H2][H2 + 1];  // gate_w transposed: gwt[k][j]
  __shared__ float lws[H2][NC + 1];
  __shared__ float rowh[4][H2];
  __shared__ float rowg[4][H2];
  int tid = threadIdx.x;

  {
    float4 w = ((const float4*)gate_w)[tid];  // H2*H2/4 == 256
    int j = (tid * 4) / H2, k = (tid * 4) % H2;
    gwt[k + 0][j] = w.x; gwt[k + 1][j] = w.y; gwt[k + 2][j] = w.z; gwt[k + 3][j] = w.w;
  }
  lws[tid >> 3][tid & 7] = leaf_w[tid];  // H2*NC == 256

  int lane = tid & 63;
  int wv = __builtin_amdgcn_readfirstlane(tid >> 6);
  int wid0 = blockIdx.x * 4 + wv;
  int wid = wid0 < n ? wid0 : n - 1;
  int q = lane >> 4, f2 = lane & 15;

  float ax = 0.f, ay = 0.f;
  if (q == 0) {  // self term
    u32 u = hp[(size_t)wid * (H2 / 2) + f2];
    ax = bf_lo(u); ay = bf_hi(u);
  }
  int r0 = off[wid], r1 = off[wid + 1];
  for (int i = r0 + q; i < r1; i += 4) {
    u32 u = hp[(size_t)csr[i] * (H2 / 2) + f2];
    ax += bf_lo(u);
    ay += bf_hi(u);
  }
  ax += __shfl_down(ax, 32, 64); ay += __shfl_down(ay, 32, 64);
  ax += __shfl_down(ax, 16, 64); ay += __shfl_down(ay, 16, 64);
  float d = dinv[wid];
  if (lane < 16) {
    float2 rv;
    rv.x = ax * d + b2[2 * f2 + 0];
    rv.y = ay * d + b2[2 * f2 + 1];
    *(float2*)&rowh[wv][2 * f2] = rv;
  }
  __syncthreads();

  // gates: j = f, half-wave split over k (16 each)
  int half = lane >> 5, f = lane & 31;
  float g = 0.f;
#pragma unroll
  for (int k = 0; k < 16; ++k) {
    int kk = half * 16 + k;
    g += rowh[wv][kk] * gwt[kk][f];
  }
  g += __shfl_down(g, 32, 64);
  if (half == 0) rowg[wv][f] = 1.0f / (1.0f + __expf(-(g + gate_b[f])));
  __syncthreads();

  // leaf: 8 groups of 8 lanes
  int c = lane & 7, gi = lane >> 3;
  float a = 0.f;
#pragma unroll
  for (int j4 = 0; j4 < 4; ++j4) {
    int jj = gi * 4 + j4;
    a += rowg[wv][jj] * lws[jj][c];
  }
  a += __shfl_down(a, 32, 64);
  a += __shfl_down(a, 16, 64);
  a += __shfl_down(a, 8, 64);
  if (lane < 8 && wid0 < n) out[(size_t)wid0 * NC + lane] = a;
}

// ---------------- host ----------------

extern "C" void kernel_launch(void* const* d_in, const int* in_sizes, int n_in,
                              void* d_out, int out_size, void* d_ws, size_t ws_size,
                              hipStream_t stream) {
  const float* x  = (const float*)d_in[0];
  const int*   ei = (const int*)d_in[1];
  const float* W1 = (const float*)d_in[2];
  const float* b1 = (const float*)d_in[3];
  const float* W2 = (const float*)d_in[4];
  const float* b2 = (const float*)d_in[5];
  const float* gw = (const float*)d_in[6];
  const float* gb = (const float*)d_in[7];
  const float* lw = (const float*)d_in[8];
  float* out = (float*)d_out;

  int n = in_sizes[0] / IN_DIM;
  int E = in_sizes[1] / 2;
  const int* src  = ei;
  const int* dstp = ei + E;

  int nb = (n + SCAN_CH - 1) / SCAN_CH;

  // workspace layout (16B-aligned chunks)
  size_t n4  = ((size_t)n + 3) & ~(size_t)3;
  size_t np4 = ((size_t)n + 1 + 3) & ~(size_t)3;
  size_t nb4 = ((size_t)nb + 3) & ~(size_t)3;
  size_t E4  = ((size_t)E + 3) & ~(size_t)3;
  char* w = (char*)d_ws;
  int* csr          = (int*)w;            w += E4 * 4;
  int* rank         = (int*)w;            w += E4 * 4;
  unsigned int* deg = (unsigned int*)w;   w += n4 * 4;
  float* dinv       = (float*)w;          w += n4 * 4;
  int* off          = (int*)w;            w += np4 * 4;
  int* bsum         = (int*)w;            w += nb4 * 4;
  int* bbase        = (int*)w;            w += nb4 * 4;
  unsigned short* h1p = (unsigned short*)w;  w += n4 * (size_t)H1 * 2;  // bf16 [n][64]
  unsigned short* h2p = (unsigned short*)w;                             // bf16 [n][32]

  int gE4 = ((E + 3) / 4 + 255) / 256;
  int gw4 = (n + 3) / 4;  // 4 nodes per 256-thread block

  hipMemsetAsync(deg, 0, (size_t)n * 4, stream);
  k_count_rank<<<gE4, 256, 0, stream>>>(dstp, deg, rank, E);
  k_scan1<<<nb, 256, 0, stream>>>(deg, dinv, bsum, n);
  k_scan2<<<1, 256, 0, stream>>>(bsum, bbase, off, nb, n);
  k_scan3<<<nb, 256, 0, stream>>>(deg, bbase, off, n);
  k_fill2<<<gE4, 256, 0, stream>>>(src, dstp, rank, off, csr, E);

  k_proj1<<<(n + 15) / 16, 256, 0, stream>>>((const float4*)x, W1, dinv, h1p, n);
  k_agg64_proj2<<<gw4, 256, 0, stream>>>((const u32*)h1p, dinv, off, csr, b1, W2, h2p, n);
  k_agg32_tree<<<gw4, 256, 0, stream>>>((const u32*)h2p, dinv, off, csr, b2, gw, gb, lw, out, n);
}

// Round 7
// 518.515 us; speedup vs baseline: 8.8834x; 1.2137x over previous
//
#include <hip/hip_runtime.h>
#include <math.h>

#define IN_DIM 128
#define H1 64
#define H2 32
#define NC 8
#define SCAN_CH 1024  // elements per scan block (256 threads x 4)

typedef unsigned int u32;

__device__ __forceinline__ float bf_lo(u32 u) { return __uint_as_float(u << 16); }
__device__ __forceinline__ float bf_hi(u32 u) { return __uint_as_float(u & 0xffff0000u); }
__device__ __forceinline__ unsigned short f2b(float f) {  // RNE float->bf16
  u32 u = __float_as_uint(f);
  u += 0x7fffu + ((u >> 16) & 1u);
  return (unsigned short)(u >> 16);
}

// ---------------- fused degree count + per-edge rank ----------------
// deg[] pre-zeroed; rank[e] = #earlier edges with same dst (atomic order).

__global__ void k_count_rank(const int* __restrict__ dst, unsigned int* __restrict__ deg,
                             int* __restrict__ rank, int E) {
  int i = (blockIdx.x * 256 + threadIdx.x) * 4;
  if (i + 3 < E) {
    int4 d = *(const int4*)(dst + i);
    int4 r;
    r.x = (int)atomicAdd(&deg[d.x], 1u);
    r.y = (int)atomicAdd(&deg[d.y], 1u);
    r.z = (int)atomicAdd(&deg[d.z], 1u);
    r.w = (int)atomicAdd(&deg[d.w], 1u);
    *(int4*)(rank + i) = r;
  } else {
    for (int j = i; j < E; ++j) rank[j] = (int)atomicAdd(&deg[dst[j]], 1u);
  }
}

// ---- 3-phase multi-block exclusive scan of count, fused dinv = rsqrt(count+1) ----

__global__ __launch_bounds__(256) void k_scan1(const unsigned int* __restrict__ deg,
                                               float* __restrict__ dinv,
                                               int* __restrict__ bsum, int n) {
  int b = blockIdx.x, tid = threadIdx.x;
  int i0 = b * SCAN_CH + tid * 4;
  int s = 0;
  if (i0 + 3 < n) {
    uint4 d = *(const uint4*)(deg + i0);
    s = (int)(d.x + d.y + d.z + d.w);
    float4 dv;
    dv.x = rsqrtf((float)(d.x + 1u)); dv.y = rsqrtf((float)(d.y + 1u));
    dv.z = rsqrtf((float)(d.z + 1u)); dv.w = rsqrtf((float)(d.w + 1u));
    *(float4*)(dinv + i0) = dv;
  } else {
    for (int i = i0; i < n; ++i) {
      unsigned int dg = deg[i];
      s += (int)dg;
      dinv[i] = rsqrtf((float)(dg + 1u));
    }
  }
  __shared__ int red[256];
  red[tid] = s;
  __syncthreads();
  for (int d = 128; d > 0; d >>= 1) {
    if (tid < d) red[tid] += red[tid + d];
    __syncthreads();
  }
  if (tid == 0) bsum[b] = red[0];
}

__global__ __launch_bounds__(256) void k_scan2(const int* __restrict__ bsum,
                                               int* __restrict__ bbase,
                                               int* __restrict__ off, int nb, int n) {
  __shared__ int part[256];
  int tid = threadIdx.x;
  int chunk = (nb + 255) / 256;
  int st = tid * chunk, en = st + chunk; if (en > nb) en = nb;
  int s = 0;
  for (int i = st; i < en; ++i) s += bsum[i];
  part[tid] = s;
  __syncthreads();
  for (int d = 1; d < 256; d <<= 1) {
    int t = (tid >= d) ? part[tid - d] : 0;
    __syncthreads();
    part[tid] += t;
    __syncthreads();
  }
  int base = (tid == 0) ? 0 : part[tid - 1];
  for (int i = st; i < en; ++i) { bbase[i] = base; base += bsum[i]; }
  if (tid == 255) off[n] = part[255];
}

__global__ __launch_bounds__(256) void k_scan3(const unsigned int* __restrict__ deg,
                                               const int* __restrict__ bbase,
                                               int* __restrict__ off, int n) {
  int b = blockIdx.x, tid = threadIdx.x;
  int i0 = b * SCAN_CH + tid * 4;
  int e0 = 0, e1 = 0, e2 = 0, e3 = 0;
  if (i0 + 3 < n) {
    uint4 d = *(const uint4*)(deg + i0);
    e0 = (int)d.x; e1 = (int)d.y; e2 = (int)d.z; e3 = (int)d.w;
  } else {
    if (i0 + 0 < n) e0 = (int)deg[i0 + 0];
    if (i0 + 1 < n) e1 = (int)deg[i0 + 1];
    if (i0 + 2 < n) e2 = (int)deg[i0 + 2];
    if (i0 + 3 < n) e3 = (int)deg[i0 + 3];
  }
  __shared__ int part[256];
  part[tid] = e0 + e1 + e2 + e3;
  __syncthreads();
  for (int d = 1; d < 256; d <<= 1) {
    int t = (tid >= d) ? part[tid - d] : 0;
    __syncthreads();
    part[tid] += t;
    __syncthreads();
  }
  int base = bbase[b] + ((tid == 0) ? 0 : part[tid - 1]);
  int o0 = base, o1 = o0 + e0, o2 = o1 + e1, o3 = o2 + e2;
  if (i0 + 3 < n) {
    int4 o; o.x = o0; o.y = o1; o.z = o2; o.w = o3;
    *(int4*)(off + i0) = o;
  } else {
    if (i0 + 0 < n) off[i0 + 0] = o0;
    if (i0 + 1 < n) off[i0 + 1] = o1;
    if (i0 + 2 < n) off[i0 + 2] = o2;
    if (i0 + 3 < n) off[i0 + 3] = o3;
  }
}

// ---------------- atomic-free CSR fill ----------------

__global__ void k_fill2(const int* __restrict__ src, const int* __restrict__ dst,
                        const int* __restrict__ rank, const int* __restrict__ off,
                        int* __restrict__ csr, int E) {
  int i = (blockIdx.x * 256 + threadIdx.x) * 4;
  if (i + 3 < E) {
    int4 s4 = *(const int4*)(src + i);
    int4 d4 = *(const int4*)(dst + i);
    int4 r4 = *(const int4*)(rank + i);
    csr[off[d4.x] + r4.x] = s4.x;
    csr[off[d4.y] + r4.y] = s4.y;
    csr[off[d4.z] + r4.z] = s4.z;
    csr[off[d4.w] + r4.w] = s4.w;
  } else {
    for (int j = i; j < E; ++j) csr[off[dst[j]] + rank[j]] = src[j];
  }
}

// ---------------- projection 1: h1p = bf16(dinv * (x @ W1^T))  [n,128]->[n,64] ----------------

__global__ void k_proj1(const float4* __restrict__ x4, const float* __restrict__ W1,
                        const float* __restrict__ dinv,
                        unsigned short* __restrict__ h1p, int n) {
  __shared__ float xs[16][IN_DIM];
  __shared__ float wt[IN_DIM][H1 + 1];
  int tid = threadIdx.x;
  int row0 = blockIdx.x * 16;

  for (int i = tid; i < (H1 * IN_DIM / 4); i += 256) {
    float4 w = ((const float4*)W1)[i];
    int o = (i * 4) / IN_DIM;
    int k = (i * 4) % IN_DIM;
    wt[k + 0][o] = w.x; wt[k + 1][o] = w.y; wt[k + 2][o] = w.z; wt[k + 3][o] = w.w;
  }
  for (int i = tid; i < 16 * IN_DIM / 4; i += 256) {
    int r = (i * 4) / IN_DIM, k = (i * 4) % IN_DIM;
    int row = row0 + r;
    if (row < n)
      *((float4*)&xs[r][k]) = x4[(size_t)row * (IN_DIM / 4) + k / 4];
  }
  __syncthreads();

  int o = tid & 63, rq = tid >> 6;
  float a0 = 0.f, a1 = 0.f, a2 = 0.f, a3 = 0.f;
  for (int k = 0; k < IN_DIM; ++k) {
    float w = wt[k][o];
    a0 += xs[rq * 4 + 0][k] * w;
    a1 += xs[rq * 4 + 1][k] * w;
    a2 += xs[rq * 4 + 2][k] * w;
    a3 += xs[rq * 4 + 3][k] * w;
  }
  int r = row0 + rq * 4;
  if (r + 0 < n) h1p[(size_t)(r + 0) * H1 + o] = f2b(a0 * dinv[r + 0]);
  if (r + 1 < n) h1p[(size_t)(r + 1) * H1 + o] = f2b(a1 * dinv[r + 1]);
  if (r + 2 < n) h1p[(size_t)(r + 2) * H1 + o] = f2b(a2 * dinv[r + 2]);
  if (r + 3 < n) h1p[(size_t)(r + 3) * H1 + o] = f2b(a3 * dinv[r + 3]);
}

// ---------------- fused: layer-1 gather-agg + bias + relu + proj2 ----------------
// Half-wave = one edge's 64 feats (u32 bf16x2/lane); 2 edges/iter baseline,
// manually unrolled x4 => 8 edges in flight per wave (MLP for latency hiding).

__global__ __launch_bounds__(256) void k_agg64_proj2(
    const u32* __restrict__ hp,    // [n][32] packed bf16x2
    const float* __restrict__ dinv,
    const int* __restrict__ off, const int* __restrict__ csr,
    const float* __restrict__ b1, const float* __restrict__ W2,
    unsigned short* __restrict__ h2p, int n) {
  __shared__ float wt[H1][H2 + 1];   // W2 transposed: wt[k][o]
  __shared__ float rows[4][H1];      // relu(out1) row per wave
  int tid = threadIdx.x;

  for (int i = tid; i < H2 * H1 / 4; i += 256) {
    float4 w = ((const float4*)W2)[i];
    int o = (i * 4) / H1, k = (i * 4) % H1;
    wt[k + 0][o] = w.x; wt[k + 1][o] = w.y; wt[k + 2][o] = w.z; wt[k + 3][o] = w.w;
  }

  int lane = tid & 63;
  int wv = __builtin_amdgcn_readfirstlane(tid >> 6);
  int wid0 = blockIdx.x * 4 + wv;
  int wid = wid0 < n ? wid0 : n - 1;   // clamp so all waves reach barriers
  int half = lane >> 5, f2 = lane & 31;

  float ax = 0.f, ay = 0.f;
  if (half == 0) {  // self term (table already has dinv[self] folded in)
    u32 u = hp[(size_t)wid * (H1 / 2) + f2];
    ax = bf_lo(u); ay = bf_hi(u);
  }
  int r0 = off[wid], r1 = off[wid + 1];
  int i = r0 + half;
  // 4 independent index loads, then 4 independent gathers per iteration
  for (; i + 6 < r1; i += 8) {
    int s0 = csr[i + 0], s1 = csr[i + 2], s2 = csr[i + 4], s3 = csr[i + 6];
    u32 u0 = hp[(size_t)s0 * (H1 / 2) + f2];
    u32 u1 = hp[(size_t)s1 * (H1 / 2) + f2];
    u32 u2 = hp[(size_t)s2 * (H1 / 2) + f2];
    u32 u3 = hp[(size_t)s3 * (H1 / 2) + f2];
    ax += bf_lo(u0); ay += bf_hi(u0);
    ax += bf_lo(u1); ay += bf_hi(u1);
    ax += bf_lo(u2); ay += bf_hi(u2);
    ax += bf_lo(u3); ay += bf_hi(u3);
  }
  for (; i < r1; i += 2) {
    u32 u = hp[(size_t)csr[i] * (H1 / 2) + f2];
    ax += bf_lo(u);
    ay += bf_hi(u);
  }
  ax += __shfl_down(ax, 32, 64);
  ay += __shfl_down(ay, 32, 64);
  float d = dinv[wid];
  if (half == 0) {
    float2 rv;
    rv.x = fmaxf(ax * d + b1[2 * f2 + 0], 0.f);
    rv.y = fmaxf(ay * d + b1[2 * f2 + 1], 0.f);
    *(float2*)&rows[wv][2 * f2] = rv;
  }
  __syncthreads();

  // proj2: half-wave split over k, 32 outputs per node
  int o = lane & 31;
  float a = 0.f;
#pragma unroll
  for (int k = 0; k < 32; ++k) {
    int kk = half * 32 + k;
    a += rows[wv][kk] * wt[kk][o];
  }
  a += __shfl_down(a, 32, 64);
  if (half == 0 && wid0 < n) h2p[(size_t)wid0 * H2 + o] = f2b(a * d);
}

// ---------------- fused: layer-2 gather-agg + b2 + gates + leaf ----------------
// Quarter-wave = one edge's 32 feats; 4 edges/iter baseline, unrolled x4 =>
// 16 edges in flight per wave.

__global__ __launch_bounds__(256) void k_agg32_tree(
    const u32* __restrict__ hp,    // [n][16] packed bf16x2
    const float* __restrict__ dinv,
    const int* __restrict__ off, const int* __restrict__ csr,
    const float* __restrict__ b2, const float* __restrict__ gate_w,
    const float* __restrict__ gate_b, const float* __restrict__ leaf_w,
    float* __restrict__ out, int n) {
  __shared__ float gwt[H2][H2 + 1];  // gate_w transposed: gwt[k][j]
  __shared__ float lws[H2][NC + 1];
  __shared__ float rowh[4][H2];
  __shared__ float rowg[4][H2];
  int tid = threadIdx.x;

  {
    float4 w = ((const float4*)gate_w)[tid];  // H2*H2/4 == 256
    int j = (tid * 4) / H2, k = (tid * 4) % H2;
    gwt[k + 0][j] = w.x; gwt[k + 1][j] = w.y; gwt[k + 2][j] = w.z; gwt[k + 3][j] = w.w;
  }
  lws[tid >> 3][tid & 7] = leaf_w[tid];  // H2*NC == 256

  int lane = tid & 63;
  int wv = __builtin_amdgcn_readfirstlane(tid >> 6);
  int wid0 = blockIdx.x * 4 + wv;
  int wid = wid0 < n ? wid0 : n - 1;
  int q = lane >> 4, f2 = lane & 15;

  float ax = 0.f, ay = 0.f;
  if (q == 0) {  // self term
    u32 u = hp[(size_t)wid * (H2 / 2) + f2];
    ax = bf_lo(u); ay = bf_hi(u);
  }
  int r0 = off[wid], r1 = off[wid + 1];
  int i = r0 + q;
  for (; i + 12 < r1; i += 16) {
    int s0 = csr[i + 0], s1 = csr[i + 4], s2 = csr[i + 8], s3 = csr[i + 12];
    u32 u0 = hp[(size_t)s0 * (H2 / 2) + f2];
    u32 u1 = hp[(size_t)s1 * (H2 / 2) + f2];
    u32 u2 = hp[(size_t)s2 * (H2 / 2) + f2];
    u32 u3 = hp[(size_t)s3 * (H2 / 2) + f2];
    ax += bf_lo(u0); ay += bf_hi(u0);
    ax += bf_lo(u1); ay += bf_hi(u1);
    ax += bf_lo(u2); ay += bf_hi(u2);
    ax += bf_lo(u3); ay += bf_hi(u3);
  }
  for (; i < r1; i += 4) {
    u32 u = hp[(size_t)csr[i] * (H2 / 2) + f2];
    ax += bf_lo(u);
    ay += bf_hi(u);
  }
  ax += __shfl_down(ax, 32, 64); ay += __shfl_down(ay, 32, 64);
  ax += __shfl_down(ax, 16, 64); ay += __shfl_down(ay, 16, 64);
  float d = dinv[wid];
  if (lane < 16) {
    float2 rv;
    rv.x = ax * d + b2[2 * f2 + 0];
    rv.y = ay * d + b2[2 * f2 + 1];
    *(float2*)&rowh[wv][2 * f2] = rv;
  }
  __syncthreads();

  // gates: j = f, half-wave split over k (16 each)
  int half = lane >> 5, f = lane & 31;
  float g = 0.f;
#pragma unroll
  for (int k = 0; k < 16; ++k) {
    int kk = half * 16 + k;
    g += rowh[wv][kk] * gwt[kk][f];
  }
  g += __shfl_down(g, 32, 64);
  if (half == 0) rowg[wv][f] = 1.0f / (1.0f + __expf(-(g + gate_b[f])));
  __syncthreads();

  // leaf: 8 groups of 8 lanes
  int c = lane & 7, gi = lane >> 3;
  float a = 0.f;
#pragma unroll
  for (int j4 = 0; j4 < 4; ++j4) {
    int jj = gi * 4 + j4;
    a += rowg[wv][jj] * lws[jj][c];
  }
  a += __shfl_down(a, 32, 64);
  a += __shfl_down(a, 16, 64);
  a += __shfl_down(a, 8, 64);
  if (lane < 8 && wid0 < n) out[(size_t)wid0 * NC + lane] = a;
}

// ---------------- host ----------------

extern "C" void kernel_launch(void* const* d_in, const int* in_sizes, int n_in,
                              void* d_out, int out_size, void* d_ws, size_t ws_size,
                              hipStream_t stream) {
  const float* x  = (const float*)d_in[0];
  const int*   ei = (const int*)d_in[1];
  const float* W1 = (const float*)d_in[2];
  const float* b1 = (const float*)d_in[3];
  const float* W2 = (const float*)d_in[4];
  const float* b2 = (const float*)d_in[5];
  const float* gw = (const float*)d_in[6];
  const float* gb = (const float*)d_in[7];
  const float* lw = (const float*)d_in[8];
  float* out = (float*)d_out;

  int n = in_sizes[0] / IN_DIM;
  int E = in_sizes[1] / 2;
  const int* src  = ei;
  const int* dstp = ei + E;

  int nb = (n + SCAN_CH - 1) / SCAN_CH;

  // workspace layout (16B-aligned chunks)
  size_t n4  = ((size_t)n + 3) & ~(size_t)3;
  size_t np4 = ((size_t)n + 1 + 3) & ~(size_t)3;
  size_t nb4 = ((size_t)nb + 3) & ~(size_t)3;
  size_t E4  = ((size_t)E + 3) & ~(size_t)3;
  char* w = (char*)d_ws;
  int* csr          = (int*)w;            w += E4 * 4;
  int* rank         = (int*)w;            w += E4 * 4;
  unsigned int* deg = (unsigned int*)w;   w += n4 * 4;
  float* dinv       = (float*)w;          w += n4 * 4;
  int* off          = (int*)w;            w += np4 * 4;
  int* bsum         = (int*)w;            w += nb4 * 4;
  int* bbase        = (int*)w;            w += nb4 * 4;
  unsigned short* h1p = (unsigned short*)w;  w += n4 * (size_t)H1 * 2;  // bf16 [n][64]
  unsigned short* h2p = (unsigned short*)w;                             // bf16 [n][32]

  int gE4 = ((E + 3) / 4 + 255) / 256;
  int gw4 = (n + 3) / 4;  // 4 nodes per 256-thread block

  hipMemsetAsync(deg, 0, (size_t)n * 4, stream);
  k_count_rank<<<gE4, 256, 0, stream>>>(dstp, deg, rank, E);
  k_scan1<<<nb, 256, 0, stream>>>(deg, dinv, bsum, n);
  k_scan2<<<1, 256, 0, stream>>>(bsum, bbase, off, nb, n);
  k_scan3<<<nb, 256, 0, stream>>>(deg, bbase, off, n);
  k_fill2<<<gE4, 256, 0, stream>>>(src, dstp, rank, off, csr, E);

  k_proj1<<<(n + 15) / 16, 256, 0, stream>>>((const float4*)x, W1, dinv, h1p, n);
  k_agg64_proj2<<<gw4, 256, 0, stream>>>((const u32*)h1p, dinv, off, csr, b1, W2, h2p, n);
  k_agg32_tree<<<gw4, 256, 0, stream>>>((const u32*)h2p, dinv, off, csr, b2, gw, gb, lw, out, n);
}